// Round 5
// baseline (2323.168 us; speedup 1.0000x reference)
//
#include <hip/hip_runtime.h>
#include <hip/hip_bf16.h>

typedef __hip_bfloat16 bf16;
typedef __attribute__((ext_vector_type(8))) short frag8;   // 8 bf16 = 4 VGPRs
typedef __attribute__((ext_vector_type(4))) float f32x4;

#define BM 64
#define BN 128
#define BK 64
#define SK 72   // padded LDS row stride (bf16): kills pow2 bank conflicts (2-way max = free)

__device__ __forceinline__ float sigm(float x) { return 1.f / (1.f + __expf(-x)); }

// C[m,n] = sum_k A[m,k] * W[n,k]; A [M,K] bf16 row-major (lda), W [N,K] bf16 (ldw).
// Tiles: 64m x 128n, K-step 64. Register-prefetch staging (VGPR->LDS, padded).
// outmode: 0 fp32, 1 bf16, 2 sigmoid(acc+bias[n]) fp32 n<nbound, 3 raw fp32 n<nbound.
__global__ __launch_bounds__(256, 4)
void gemm_bt(const bf16* __restrict__ A, int lda, long long sAz,
             const bf16* __restrict__ W, int ldw, long long sWz,
             void* __restrict__ Cv, int ldc, long long sCz, int K,
             int outmode, const float* __restrict__ bias, int nbound)
{
    __shared__ short As[BM * SK];
    __shared__ short Bs[BN * SK];
    const int z = blockIdx.z;
    A += (size_t)z * sAz;
    W += (size_t)z * sWz;
    const int m0 = blockIdx.y * BM;
    const int n0 = blockIdx.x * BN;
    const int tid  = threadIdx.x;
    const int lane = tid & 63;
    const int wave = tid >> 6;
    const int wm = (wave >> 1) * 32;   // 2x2 waves, each 32m x 64n
    const int wn = (wave & 1) * 64;
    const int q   = lane >> 4;
    const int r16 = lane & 15;

    f32x4 acc[2][4] = {};

    const int trow = tid >> 3;         // 0..31
    const int tcol = (tid & 7) * 8;    // 16B chunk offset (bf16 elems)

    uint4 ra[2], rb[4];
    #pragma unroll
    for (int p = 0; p < 2; ++p)
        ra[p] = *(const uint4*)(A + (size_t)(m0 + p * 32 + trow) * lda + tcol);
    #pragma unroll
    for (int p = 0; p < 4; ++p)
        rb[p] = *(const uint4*)(W + (size_t)(n0 + p * 32 + trow) * ldw + tcol);

    for (int k0 = 0; k0 < K; k0 += BK) {
        if (k0) __syncthreads();
        #pragma unroll
        for (int p = 0; p < 2; ++p)
            *(uint4*)&As[(p * 32 + trow) * SK + tcol] = ra[p];
        #pragma unroll
        for (int p = 0; p < 4; ++p)
            *(uint4*)&Bs[(p * 32 + trow) * SK + tcol] = rb[p];
        __syncthreads();
        if (k0 + BK < K) {
            #pragma unroll
            for (int p = 0; p < 2; ++p)
                ra[p] = *(const uint4*)(A + (size_t)(m0 + p * 32 + trow) * lda + k0 + BK + tcol);
            #pragma unroll
            for (int p = 0; p < 4; ++p)
                rb[p] = *(const uint4*)(W + (size_t)(n0 + p * 32 + trow) * ldw + k0 + BK + tcol);
        }
        #pragma unroll
        for (int kk = 0; kk < 2; ++kk) {
            const int ko = kk * 32 + q * 8;
            frag8 af[2], bfr[4];
            #pragma unroll
            for (int i = 0; i < 2; ++i)
                af[i] = *(const frag8*)&As[(wm + i * 16 + r16) * SK + ko];
            #pragma unroll
            for (int j = 0; j < 4; ++j)
                bfr[j] = *(const frag8*)&Bs[(wn + j * 16 + r16) * SK + ko];
            #pragma unroll
            for (int i = 0; i < 2; ++i)
                #pragma unroll
                for (int j = 0; j < 4; ++j)
                    acc[i][j] = __builtin_amdgcn_mfma_f32_16x16x32_bf16(
                        af[i], bfr[j], acc[i][j], 0, 0, 0);
        }
    }

    // C/D layout: col = lane&15 (+16j+wn), row = (lane>>4)*4 + reg (+16i+wm)
    if (outmode == 0) {
        float* C = (float*)Cv + (size_t)z * sCz;
        #pragma unroll
        for (int i = 0; i < 2; ++i)
            #pragma unroll
            for (int rr = 0; rr < 4; ++rr) {
                int row = m0 + wm + i * 16 + q * 4 + rr;
                float* crow = C + (size_t)row * ldc + n0 + wn + r16;
                #pragma unroll
                for (int j = 0; j < 4; ++j) crow[j * 16] = acc[i][j][rr];
            }
    } else if (outmode == 1) {
        bf16* C = (bf16*)Cv + (size_t)z * sCz;
        #pragma unroll
        for (int i = 0; i < 2; ++i)
            #pragma unroll
            for (int rr = 0; rr < 4; ++rr) {
                int row = m0 + wm + i * 16 + q * 4 + rr;
                bf16* crow = C + (size_t)row * ldc + n0 + wn + r16;
                #pragma unroll
                for (int j = 0; j < 4; ++j) crow[j * 16] = __float2bfloat16(acc[i][j][rr]);
            }
    } else if (outmode == 2) {
        float* C = (float*)Cv + (size_t)z * sCz;
        #pragma unroll
        for (int i = 0; i < 2; ++i)
            #pragma unroll
            for (int rr = 0; rr < 4; ++rr) {
                int row = m0 + wm + i * 16 + q * 4 + rr;
                #pragma unroll
                for (int j = 0; j < 4; ++j) {
                    int col = n0 + wn + j * 16 + r16;
                    if (col < nbound)
                        C[(size_t)row * ldc + col] = sigm(acc[i][j][rr] + bias[col]);
                }
            }
    } else {
        float* C = (float*)Cv + (size_t)z * sCz;
        #pragma unroll
        for (int i = 0; i < 2; ++i)
            #pragma unroll
            for (int rr = 0; rr < 4; ++rr) {
                int row = m0 + wm + i * 16 + q * 4 + rr;
                #pragma unroll
                for (int j = 0; j < 4; ++j) {
                    int col = n0 + wn + j * 16 + r16;
                    if (col < nbound)
                        C[(size_t)row * ldc + col] = acc[i][j][rr];
                }
            }
    }
}

// ---------------- fused input-GEMM + gates (layers 1,2) ----------------
// A [4096 x 256] bf16 (row stride lda), Wi interleaved [1024][256] (n = 4*j + gate,
// f,i,o,c), Wg [16][256] (rows 0..2 = Wi_g[l], rest zero). Grid (8, 64), block 256.
struct Stage { short As[BM * SK]; short Bs[BN * SK]; short Bg[16 * SK]; };
union SMemU { Stage s; float ct[64 * 128]; };

__global__ __launch_bounds__(256, 2)
void gemm_gates(const bf16* __restrict__ A, int lda,
                const bf16* __restrict__ Wi, const bf16* __restrict__ Wg,
                const bf16* __restrict__ hg_l,   // [4096][768] bf16, f/i/o planar
                const bf16* __restrict__ aux_l,  // [4096][768] bf16
                const float* __restrict__ ghc_l, // [4096][9] fp32, +l*3, biases folded
                const float* __restrict__ cprev, // [4096*256]
                const float* __restrict__ bif, const float* __restrict__ bhf,
                const float* __restrict__ bii, const float* __restrict__ bhi,
                const float* __restrict__ bio, const float* __restrict__ bho,
                const float* __restrict__ bic, const float* __restrict__ bhc, // [768]
                bf16*  __restrict__ hnew,   // col-slice base, row stride 768
                float* __restrict__ cnew,
                bf16*  __restrict__ featc)  // nullable, row stride 2304
{
    __shared__ SMemU sm;
    __shared__ float gsh[64 * 3];

    const int m0 = blockIdx.y * BM;
    const int n0 = blockIdx.x * BN;
    const int jbase = n0 >> 2;          // 32 j's per block
    const int tid  = threadIdx.x;
    const int lane = tid & 63;
    const int wave = tid >> 6;
    const int wm = (wave >> 1) * 32;
    const int wn = (wave & 1) * 64;
    const int q   = lane >> 4;
    const int r16 = lane & 15;

    f32x4 acc[2][4] = {};
    f32x4 accg[2] = {};

    const int trow = tid >> 3;
    const int tcol = (tid & 7) * 8;

    uint4 ra[2], rb[4], rg;
    #pragma unroll
    for (int p = 0; p < 2; ++p)
        ra[p] = *(const uint4*)(A + (size_t)(m0 + p * 32 + trow) * lda + tcol);
    #pragma unroll
    for (int p = 0; p < 4; ++p)
        rb[p] = *(const uint4*)(Wi + (size_t)(n0 + p * 32 + trow) * 256 + tcol);
    if (tid < 128)
        rg = *(const uint4*)(Wg + (size_t)(tid >> 3) * 256 + tcol);

    for (int k0 = 0; k0 < 256; k0 += BK) {
        if (k0) __syncthreads();
        #pragma unroll
        for (int p = 0; p < 2; ++p)
            *(uint4*)&sm.s.As[(p * 32 + trow) * SK + tcol] = ra[p];
        #pragma unroll
        for (int p = 0; p < 4; ++p)
            *(uint4*)&sm.s.Bs[(p * 32 + trow) * SK + tcol] = rb[p];
        if (tid < 128)
            *(uint4*)&sm.s.Bg[(tid >> 3) * SK + tcol] = rg;
        __syncthreads();
        if (k0 + BK < 256) {
            #pragma unroll
            for (int p = 0; p < 2; ++p)
                ra[p] = *(const uint4*)(A + (size_t)(m0 + p * 32 + trow) * lda + k0 + BK + tcol);
            #pragma unroll
            for (int p = 0; p < 4; ++p)
                rb[p] = *(const uint4*)(Wi + (size_t)(n0 + p * 32 + trow) * 256 + k0 + BK + tcol);
            if (tid < 128)
                rg = *(const uint4*)(Wg + (size_t)(tid >> 3) * 256 + k0 + BK + tcol);
        }
        #pragma unroll
        for (int kk = 0; kk < 2; ++kk) {
            const int ko = kk * 32 + q * 8;
            frag8 af[2], bfr[4], bg;
            bg = *(const frag8*)&sm.s.Bg[r16 * SK + ko];
            #pragma unroll
            for (int i = 0; i < 2; ++i)
                af[i] = *(const frag8*)&sm.s.As[(wm + i * 16 + r16) * SK + ko];
            #pragma unroll
            for (int j = 0; j < 4; ++j)
                bfr[j] = *(const frag8*)&sm.s.Bs[(wn + j * 16 + r16) * SK + ko];
            #pragma unroll
            for (int i = 0; i < 2; ++i) {
                #pragma unroll
                for (int j = 0; j < 4; ++j)
                    acc[i][j] = __builtin_amdgcn_mfma_f32_16x16x32_bf16(
                        af[i], bfr[j], acc[i][j], 0, 0, 0);
                accg[i] = __builtin_amdgcn_mfma_f32_16x16x32_bf16(
                    af[i], bg, accg[i], 0, 0, 0);
            }
        }
    }

    __syncthreads();   // staging reads done; sm union becomes ct
    // g values: wn==0 waves (0,2) cover rows 0..63, lanes r16<3
    if (wn == 0 && r16 < 3) {
        #pragma unroll
        for (int i = 0; i < 2; ++i)
            #pragma unroll
            for (int rr = 0; rr < 4; ++rr) {
                int row = wm + i * 16 + q * 4 + rr;
                gsh[row * 3 + r16] = sigm(accg[i][rr] + ghc_l[(size_t)(m0 + row) * 9 + r16]);
            }
    }
    // dump C tile (rotate-swizzled to keep read float4s conflict-light)
    #pragma unroll
    for (int i = 0; i < 2; ++i)
        #pragma unroll
        for (int rr = 0; rr < 4; ++rr) {
            int rowl = wm + i * 16 + q * 4 + rr;
            #pragma unroll
            for (int jr = 0; jr < 4; ++jr) {
                int col = wn + jr * 16 + r16;
                sm.ct[rowl * 128 + ((col + 4 * rowl) & 127)] = acc[i][jr][rr];
            }
        }
    __syncthreads();

    const int jj = tid & 31;
    const int r0 = (tid >> 5) * 8;
    const int j  = jbase + jj;
    const float vbif = bif[j], vbhf = bhf[j];
    const float vbii = bii[j], vbhi = bhi[j];
    const float vbio = bio[j], vbho = bho[j];
    const float vbic = bic[j];
    const float vbc0 = bhc[j], vbc1 = bhc[256 + j], vbc2 = bhc[512 + j];

    for (int ri = 0; ri < 8; ++ri) {
        int rowl = r0 + ri;
        size_t b = m0 + rowl;
        float4 pre = *(float4*)&sm.ct[rowl * 128 + ((4 * jj + 4 * rowl) & 127)];
        float g0 = gsh[rowl * 3 + 0];
        float g1 = gsh[rowl * 3 + 1];
        float g2 = gsh[rowl * 3 + 2];
        float hgf = __bfloat162float(hg_l[b * 768 + j]);
        float hgi = __bfloat162float(hg_l[b * 768 + 256 + j]);
        float hgo = __bfloat162float(hg_l[b * 768 + 512 + j]);
        float ax0 = __bfloat162float(aux_l[b * 768 + j]);
        float ax1 = __bfloat162float(aux_l[b * 768 + 256 + j]);
        float ax2 = __bfloat162float(aux_l[b * 768 + 512 + j]);
        float f  = sigm(pre.x + vbif + hgf + vbhf);
        float ii = sigm(pre.y + vbii + hgi + vbhi);
        float o  = sigm(pre.z + vbio + hgo + vbho);
        float av = g0 * (ax0 + vbc0) + g1 * (ax1 + vbc1) + g2 * (ax2 + vbc2);
        float ct = tanhf(pre.w + vbic + av);
        float c  = f * cprev[b * 256 + j] + ii * ct;
        float h  = o * c;
        cnew[b * 256 + j] = c;
        hnew[b * 768 + j] = __float2bfloat16(h);
        if (featc) featc[b * 2304 + j] = __float2bfloat16(h);
    }
}

// ---------------- layer-0 gates from precomputed pre-acts ----------------
__global__ __launch_bounds__(256)
void gates_pre(const bf16* __restrict__ ipre0i, const float* __restrict__ gin0,
               const float* __restrict__ ghc,
               const bf16* __restrict__ hg_l, const bf16* __restrict__ aux_l,
               const float* __restrict__ cprev,
               const float* __restrict__ bif, const float* __restrict__ bhf,
               const float* __restrict__ bii, const float* __restrict__ bhi,
               const float* __restrict__ bio, const float* __restrict__ bho,
               const float* __restrict__ bic, const float* __restrict__ bhc,
               bf16* __restrict__ hnew, float* __restrict__ cnew)
{
    const int j = threadIdx.x;
    const int b0 = blockIdx.x * 16;
    const float vbif = bif[j], vbhf = bhf[j];
    const float vbii = bii[j], vbhi = bhi[j];
    const float vbio = bio[j], vbho = bho[j];
    const float vbic = bic[j];
    const float vbc0 = bhc[j], vbc1 = bhc[256 + j], vbc2 = bhc[512 + j];

    for (int r = 0; r < 16; ++r) {
        const size_t b = b0 + r;
        const bf16* ip4 = ipre0i + b * 1024 + 4 * j;
        float pf = __bfloat162float(ip4[0]);
        float pi = __bfloat162float(ip4[1]);
        float po = __bfloat162float(ip4[2]);
        float pc = __bfloat162float(ip4[3]);
        float g0 = sigm(gin0[b * 3 + 0] + ghc[b * 9 + 0]);
        float g1 = sigm(gin0[b * 3 + 1] + ghc[b * 9 + 1]);
        float g2 = sigm(gin0[b * 3 + 2] + ghc[b * 9 + 2]);
        float hgf = __bfloat162float(hg_l[b * 768 + j]);
        float hgi = __bfloat162float(hg_l[b * 768 + 256 + j]);
        float hgo = __bfloat162float(hg_l[b * 768 + 512 + j]);
        float ax0 = __bfloat162float(aux_l[b * 768 + j]);
        float ax1 = __bfloat162float(aux_l[b * 768 + 256 + j]);
        float ax2 = __bfloat162float(aux_l[b * 768 + 512 + j]);
        float f  = sigm(pf + vbif + hgf + vbhf);
        float ii = sigm(pi + vbii + hgi + vbhi);
        float o  = sigm(po + vbio + hgo + vbho);
        float av = g0 * (ax0 + vbc0) + g1 * (ax1 + vbc1) + g2 * (ax2 + vbc2);
        float ct = tanhf(pc + vbic + av);
        float c  = f * cprev[b * 256 + j] + ii * ct;
        float h  = o * c;
        cnew[b * 256 + j] = c;
        hnew[b * 768 + j] = __float2bfloat16(h);
    }
}

// ghcat[b][l*3+s] = h_cat[b,:] . Wh_g[l][s][:] + bi_g + bh_g. 4 waves x 4 rows/block.
__global__ __launch_bounds__(256)
void ghcat_kernel(const bf16* __restrict__ hcat, const float* __restrict__ Whg,
                  const float* __restrict__ big, const float* __restrict__ bhg,
                  float* __restrict__ gh)
{
    const int wave = threadIdx.x >> 6, lane = threadIdx.x & 63;
    for (int rep = 0; rep < 4; ++rep) {
        size_t b = (size_t)blockIdx.x * 16 + wave * 4 + rep;
        float hv[12];
        #pragma unroll
        for (int m = 0; m < 12; ++m)
            hv[m] = __bfloat162float(hcat[b * 768 + m * 64 + lane]);
        float p[9];
        #pragma unroll
        for (int s = 0; s < 9; ++s) {
            float t = 0.f;
            const float* w = Whg + (size_t)s * 768;
            #pragma unroll
            for (int m = 0; m < 12; ++m) t += hv[m] * w[m * 64 + lane];
            p[s] = t;
        }
        #pragma unroll
        for (int off = 32; off; off >>= 1)
            #pragma unroll
            for (int s = 0; s < 9; ++s) p[s] += __shfl_down(p[s], off);
        if (lane == 0) {
            #pragma unroll
            for (int s = 0; s < 9; ++s)
                gh[b * 9 + s] = p[s] + big[s] + bhg[s];
        }
    }
}

// gin0[b][s] = xb[b,:] . Wi_g[0][s][:]  (no bias; constant over t)
__global__ __launch_bounds__(256)
void gin0_kernel(const bf16* __restrict__ xb, const float* __restrict__ Wig,
                 float* __restrict__ gout)
{
    const int wave = threadIdx.x >> 6, lane = threadIdx.x & 63;
    for (int rep = 0; rep < 4; ++rep) {
        size_t b = (size_t)blockIdx.x * 16 + wave * 4 + rep;
        float hv[4];
        #pragma unroll
        for (int m = 0; m < 4; ++m)
            hv[m] = __bfloat162float(xb[b * 256 + m * 64 + lane]);
        float p[3];
        #pragma unroll
        for (int s = 0; s < 3; ++s) {
            float t = 0.f;
            const float* w = Wig + (size_t)s * 256;
            #pragma unroll
            for (int m = 0; m < 4; ++m) t += hv[m] * w[m * 64 + lane];
            p[s] = t;
        }
        #pragma unroll
        for (int off = 32; off; off >>= 1)
            #pragma unroll
            for (int s = 0; s < 3; ++s) p[s] += __shfl_down(p[s], off);
        if (lane == 0) {
            #pragma unroll
            for (int s = 0; s < 3; ++s) gout[b * 3 + s] = p[s];
        }
    }
}

// out[b][n] = sigm(bias[n] + sum_z part[z][b][n]), n<44
__global__ __launch_bounds__(256)
void final_reduce(const float* __restrict__ part, const float* __restrict__ bl,
                  float* __restrict__ out)
{
    int idx = blockIdx.x * 256 + threadIdx.x;
    if (idx >= 4096 * 44) return;
    int b = idx / 44, n = idx - b * 44;
    float s = bl[n];
    #pragma unroll
    for (int z = 0; z < 12; ++z) s += part[(size_t)z * 4096 * 64 + (size_t)b * 64 + n];
    out[idx] = sigm(s);
}

// ---------------- prep kernels ----------------
__global__ void build_wicati(const float* __restrict__ Wf, const float* __restrict__ Wi,
                             const float* __restrict__ Wo, const float* __restrict__ Wc,
                             bf16* __restrict__ out)
{
    int idx = blockIdx.x * 256 + threadIdx.x;  // 3*1024*256
    int k = idx & 255, n = (idx >> 8) & 1023, l = idx >> 18;
    int j = n >> 2, g = n & 3;
    const float* src = (g == 0) ? Wf : (g == 1) ? Wi : (g == 2) ? Wo : Wc;
    out[idx] = __float2bfloat16(src[l * 65536 + j * 256 + k]);
}

__global__ void build_whfio(const float* __restrict__ Wf, const float* __restrict__ Wi,
                            const float* __restrict__ Wo, bf16* __restrict__ out)
{
    int idx = blockIdx.x * 256 + threadIdx.x;  // 3*768*256
    int k = idx & 255, n = (idx >> 8) % 768, l = idx / 196608;
    const float* src = (n < 256) ? Wf : (n < 512) ? Wi : Wo;
    out[idx] = __float2bfloat16(src[l * 65536 + (n & 255) * 256 + k]);
}

__global__ void build_wg(const float* __restrict__ Wig, bf16* __restrict__ out)
{
    int idx = blockIdx.x * 256 + threadIdx.x;  // 3*16*256
    int k = idx & 255, r = (idx >> 8) & 15, l = idx >> 12;
    out[idx] = (r < 3) ? __float2bfloat16(Wig[l * 768 + r * 256 + k]) : __float2bfloat16(0.f);
}

__global__ void build_wlast(const float* __restrict__ Wl, bf16* __restrict__ out)
{
    int idx = blockIdx.x * 256 + threadIdx.x;  // 128*2304
    int k = idx % 2304, n = idx / 2304;
    out[idx] = (n < 44) ? __float2bfloat16(Wl[n * 2304 + k]) : __float2bfloat16(0.f);
}

__global__ void convert_f2b(const float* __restrict__ in, bf16* __restrict__ out, int n)
{
    int idx = blockIdx.x * 256 + threadIdx.x;
    if (idx < n) out[idx] = __float2bfloat16(in[idx]);
}

__global__ void init_state(const float* __restrict__ hidden0, const float* __restrict__ current0,
                           bf16* __restrict__ hcat, float* __restrict__ c0)
{
    int idx = blockIdx.x * 256 + threadIdx.x;  // 3*4096*256
    int j = idx & 255, b = (idx >> 8) & 4095, l = idx >> 20;
    hcat[(size_t)b * 768 + l * 256 + j] = __float2bfloat16(hidden0[idx]);
    c0[idx] = current0[idx];
}

extern "C" void kernel_launch(void* const* d_in, const int* in_sizes, int n_in,
                              void* d_out, int out_size, void* d_ws, size_t ws_size,
                              hipStream_t stream)
{
    (void)in_sizes; (void)n_in; (void)out_size; (void)ws_size;
    const float* x        = (const float*)d_in[0];
    const float* hidden0  = (const float*)d_in[1];
    const float* current0 = (const float*)d_in[2];
    const float* Wi_f = (const float*)d_in[3];  const float* bi_f = (const float*)d_in[4];
    const float* Wi_i = (const float*)d_in[5];  const float* bi_i = (const float*)d_in[6];
    const float* Wi_o = (const float*)d_in[7];  const float* bi_o = (const float*)d_in[8];
    const float* Wi_c = (const float*)d_in[9];  const float* bi_c = (const float*)d_in[10];
    const float* Wi_g = (const float*)d_in[11]; const float* bi_g = (const float*)d_in[12];
    const float* Wh_f = (const float*)d_in[13]; const float* bh_f = (const float*)d_in[14];
    const float* Wh_i = (const float*)d_in[15]; const float* bh_i = (const float*)d_in[16];
    const float* Wh_o = (const float*)d_in[17]; const float* bh_o = (const float*)d_in[18];
    const float* Wh_g = (const float*)d_in[19]; const float* bh_g = (const float*)d_in[20];
    const float* Wh_c = (const float*)d_in[21]; const float* bh_c = (const float*)d_in[22];
    const float* W_last = (const float*)d_in[23]; const float* b_last = (const float*)d_in[24];

    char* p = (char*)d_ws;
    bf16* WiCatI = (bf16*)p; p += (size_t)3 * 1024 * 256 * 2;
    bf16* WhFIO  = (bf16*)p; p += (size_t)3 * 768 * 256 * 2;
    bf16* WhCb   = (bf16*)p; p += (size_t)3 * 768 * 768 * 2;
    bf16* Wgb    = (bf16*)p; p += (size_t)3 * 16 * 256 * 2;
    bf16* Wlb    = (bf16*)p; p += (size_t)128 * 2304 * 2;
    bf16* xb     = (bf16*)p; p += (size_t)4096 * 256 * 2;
    bf16* ipre0i = (bf16*)p; p += (size_t)4096 * 1024 * 2;
    float* gin0  = (float*)p; p += (size_t)4096 * 3 * 4;
    bf16* hb0    = (bf16*)p; p += (size_t)4096 * 768 * 2;
    bf16* hb1    = (bf16*)p; p += (size_t)4096 * 768 * 2;
    float* cb0   = (float*)p; p += (size_t)3 * 4096 * 256 * 4;
    float* cb1   = (float*)p; p += (size_t)3 * 4096 * 256 * 4;
    bf16* hgb    = (bf16*)p; p += (size_t)3 * 4096 * 768 * 2;
    bf16* auxb   = (bf16*)p; p += (size_t)3 * 4096 * 768 * 2;
    float* gh    = (float*)p; p += (size_t)4096 * 9 * 4;
    bf16* feat   = (bf16*)p; p += (size_t)4096 * 2304 * 2;
    float* partf = (float*)p; p += (size_t)12 * 4096 * 64 * 4;

    build_wicati<<<3072, 256, 0, stream>>>(Wi_f, Wi_i, Wi_o, Wi_c, WiCatI);
    build_whfio<<<2304, 256, 0, stream>>>(Wh_f, Wh_i, Wh_o, WhFIO);
    convert_f2b<<<(3 * 768 * 768 + 255) / 256, 256, 0, stream>>>(Wh_c, WhCb, 3 * 768 * 768);
    build_wg<<<48, 256, 0, stream>>>(Wi_g, Wgb);
    build_wlast<<<1152, 256, 0, stream>>>(W_last, Wlb);
    convert_f2b<<<4096, 256, 0, stream>>>(x, xb, 4096 * 256);
    init_state<<<12288, 256, 0, stream>>>(hidden0, current0, hb0, cb0);

    // hoisted layer-0 input-side work (x constant across t)
    gemm_bt<<<dim3(8, 64, 1), 256, 0, stream>>>(xb, 256, 0, WiCatI, 256, 0,
                                                ipre0i, 1024, 0, 256, 1, nullptr, 0);
    gin0_kernel<<<256, 256, 0, stream>>>(xb, Wi_g, gin0);

    for (int t = 0; t < 10; ++t) {
        bf16* hprev = (t & 1) ? hb1 : hb0;
        bf16* hnew  = (t & 1) ? hb0 : hb1;
        float* cprev = (t & 1) ? cb1 : cb0;
        float* cnew  = (t & 1) ? cb0 : cb1;

        gemm_bt<<<dim3(6, 64, 3), 256, 0, stream>>>(
            hprev, 768, 256, WhFIO, 256, (long long)768 * 256,
            hgb, 768, (long long)4096 * 768, 256, 1, nullptr, 0);
        gemm_bt<<<dim3(6, 64, 3), 256, 0, stream>>>(
            hprev, 768, 0, WhCb, 768, (long long)768 * 768,
            auxb, 768, (long long)4096 * 768, 768, 1, nullptr, 0);
        ghcat_kernel<<<256, 256, 0, stream>>>(hprev, Wh_g, bi_g, bh_g, gh);

        gates_pre<<<256, 256, 0, stream>>>(
            ipre0i, gin0, gh,
            hgb, auxb, cprev,
            bi_f, bh_f, bi_i, bh_i, bi_o, bh_o, bi_c, bh_c,
            hnew, cnew);

        for (int l = 1; l < 3; ++l) {
            gemm_gates<<<dim3(8, 64), 256, 0, stream>>>(
                (const bf16*)(hnew + (l - 1) * 256), 768,
                WiCatI + (size_t)l * 1024 * 256,
                Wgb + (size_t)l * 16 * 256,
                hgb + (size_t)l * 4096 * 768,
                auxb + (size_t)l * 4096 * 768,
                gh + l * 3,
                cprev + (size_t)l * 4096 * 256,
                bi_f + l * 256, bh_f + l * 256,
                bi_i + l * 256, bh_i + l * 256,
                bi_o + l * 256, bh_o + l * 256,
                bi_c + l * 256, bh_c + l * 768,
                hnew + l * 256,
                cnew + (size_t)l * 4096 * 256,
                (l == 2 && t < 9) ? (feat + (size_t)t * 256) : (bf16*)nullptr);
        }
    }

    // final: K-split feat[4096,2304] @ Wlb[128,2304]^T into 12 partials of K=192
    gemm_bt<<<dim3(1, 64, 12), 256, 0, stream>>>(
        feat, 2304, 192, Wlb, 2304, 192,
        partf, 64, (long long)4096 * 64, 192, 3, nullptr, 64);
    final_reduce<<<704, 256, 0, stream>>>(partf, b_last, (float*)d_out);
}

// Round 6
// 2007.526 us; speedup vs baseline: 1.1572x; 1.1572x over previous
//
#include <hip/hip_runtime.h>
#include <hip/hip_bf16.h>

typedef __hip_bfloat16 bf16;
typedef __attribute__((ext_vector_type(8))) short frag8;   // 8 bf16 = 4 VGPRs
typedef __attribute__((ext_vector_type(4))) float f32x4;

#define BM 128
#define BN 128
#define BK 64
#define SK 72   // padded LDS row stride (bf16): max 2-way bank aliasing (free, m136)

__device__ __forceinline__ float sigm(float x) { return 1.f / (1.f + __expf(-x)); }

// C[m,n] = sum_k A[m,k] * W[n,k]; A [M,K] bf16 (lda), W [N,K] bf16 (ldw). 128x128 tile.
// VGPR double-buffer prefetch -> padded LDS. launch_bounds(256,2): no spill (r5 lesson).
// outmode: 0 fp32, 1 bf16, 2 sigmoid(acc+bias[n]) fp32 n<nbound, 3 raw fp32 n<nbound.
__global__ __launch_bounds__(256, 2)
void gemm_bt(const bf16* __restrict__ A, int lda, long long sAz,
             const bf16* __restrict__ W, int ldw, long long sWz,
             void* __restrict__ Cv, int ldc, long long sCz, int K,
             int outmode, const float* __restrict__ bias, int nbound)
{
    __shared__ short As[BM * SK];
    __shared__ short Bs[BN * SK];
    const int z = blockIdx.z;
    A += (size_t)z * sAz;
    W += (size_t)z * sWz;
    const int m0 = blockIdx.y * BM;
    const int n0 = blockIdx.x * BN;
    const int tid  = threadIdx.x;
    const int lane = tid & 63;
    const int wave = tid >> 6;
    const int wm = (wave >> 1) * 64;
    const int wn = (wave & 1) * 64;
    const int q   = lane >> 4;
    const int r16 = lane & 15;

    f32x4 acc[4][4] = {};

    const int trow = tid >> 3;         // 0..31
    const int tcol = (tid & 7) * 8;    // 16B chunk (bf16 elems)

    uint4 ra[4], rb[4];
    #pragma unroll
    for (int p = 0; p < 4; ++p) {
        ra[p] = *(const uint4*)(A + (size_t)(m0 + p * 32 + trow) * lda + tcol);
        rb[p] = *(const uint4*)(W + (size_t)(n0 + p * 32 + trow) * ldw + tcol);
    }

    for (int k0 = 0; k0 < K; k0 += BK) {
        if (k0) __syncthreads();
        #pragma unroll
        for (int p = 0; p < 4; ++p) {
            *(uint4*)&As[(p * 32 + trow) * SK + tcol] = ra[p];
            *(uint4*)&Bs[(p * 32 + trow) * SK + tcol] = rb[p];
        }
        __syncthreads();
        if (k0 + BK < K) {
            #pragma unroll
            for (int p = 0; p < 4; ++p) {
                ra[p] = *(const uint4*)(A + (size_t)(m0 + p * 32 + trow) * lda + k0 + BK + tcol);
                rb[p] = *(const uint4*)(W + (size_t)(n0 + p * 32 + trow) * ldw + k0 + BK + tcol);
            }
        }
        #pragma unroll
        for (int kk = 0; kk < 2; ++kk) {
            const int ko = kk * 32 + q * 8;
            frag8 af[4], bfr[4];
            #pragma unroll
            for (int i = 0; i < 4; ++i)
                af[i] = *(const frag8*)&As[(wm + i * 16 + r16) * SK + ko];
            #pragma unroll
            for (int j = 0; j < 4; ++j)
                bfr[j] = *(const frag8*)&Bs[(wn + j * 16 + r16) * SK + ko];
            #pragma unroll
            for (int i = 0; i < 4; ++i)
                #pragma unroll
                for (int j = 0; j < 4; ++j)
                    acc[i][j] = __builtin_amdgcn_mfma_f32_16x16x32_bf16(
                        af[i], bfr[j], acc[i][j], 0, 0, 0);
        }
    }

    // C/D layout: col = lane&15 (+16j+wn), row = (lane>>4)*4 + reg (+16i+wm)
    if (outmode == 0) {
        float* C = (float*)Cv + (size_t)z * sCz;
        #pragma unroll
        for (int i = 0; i < 4; ++i)
            #pragma unroll
            for (int rr = 0; rr < 4; ++rr) {
                int row = m0 + wm + i * 16 + q * 4 + rr;
                float* crow = C + (size_t)row * ldc + n0 + wn + r16;
                #pragma unroll
                for (int j = 0; j < 4; ++j) crow[j * 16] = acc[i][j][rr];
            }
    } else if (outmode == 1) {
        bf16* C = (bf16*)Cv + (size_t)z * sCz;
        #pragma unroll
        for (int i = 0; i < 4; ++i)
            #pragma unroll
            for (int rr = 0; rr < 4; ++rr) {
                int row = m0 + wm + i * 16 + q * 4 + rr;
                bf16* crow = C + (size_t)row * ldc + n0 + wn + r16;
                #pragma unroll
                for (int j = 0; j < 4; ++j) crow[j * 16] = __float2bfloat16(acc[i][j][rr]);
            }
    } else if (outmode == 2) {
        float* C = (float*)Cv + (size_t)z * sCz;
        #pragma unroll
        for (int i = 0; i < 4; ++i)
            #pragma unroll
            for (int rr = 0; rr < 4; ++rr) {
                int row = m0 + wm + i * 16 + q * 4 + rr;
                #pragma unroll
                for (int j = 0; j < 4; ++j) {
                    int col = n0 + wn + j * 16 + r16;
                    if (col < nbound)
                        C[(size_t)row * ldc + col] = sigm(acc[i][j][rr] + bias[col]);
                }
            }
    } else {
        float* C = (float*)Cv + (size_t)z * sCz;
        #pragma unroll
        for (int i = 0; i < 4; ++i)
            #pragma unroll
            for (int rr = 0; rr < 4; ++rr) {
                int row = m0 + wm + i * 16 + q * 4 + rr;
                #pragma unroll
                for (int j = 0; j < 4; ++j) {
                    int col = n0 + wn + j * 16 + r16;
                    if (col < nbound)
                        C[(size_t)row * ldc + col] = acc[i][j][rr];
                }
            }
    }
}

// ---------------- merged hidden-side kernel ----------------
// Grid (6, 32, 6). z<3: hg GEMM for layer z (A = hprev col-slice, K=256, W=WhFIO[z]).
// z>=3: aux GEMM for layer z-3 (A = full hcat, K=768, W=WhCb[l]); x==0 blocks also
// compute gh[b][l*3+s] = hcat . Wh_g[l][s] + bi_g + bh_g via a 16-row B-fragment.
__global__ __launch_bounds__(256, 2)
void gemm_hidden(const bf16* __restrict__ hprev,
                 const bf16* __restrict__ WhFIO,  // [3][768][256]
                 const bf16* __restrict__ WhCb,   // [3][768][768]
                 const bf16* __restrict__ WgH,    // [3][16][768], rows 0..2 = Wh_g[l]
                 const float* __restrict__ big, const float* __restrict__ bhg,  // [9]
                 bf16* __restrict__ hgb,          // [3][4096][768]
                 bf16* __restrict__ auxb,         // [3][4096][768]
                 float* __restrict__ gh)          // [4096][9]
{
    __shared__ short As[BM * SK];
    __shared__ short Bs[BN * SK];
    __shared__ short Bg[16 * SK];

    const int z = blockIdx.z;
    const bool isaux = z >= 3;
    const int l = isaux ? z - 3 : z;
    const bf16* A = hprev + (isaux ? 0 : l * 256);
    const int K = isaux ? 768 : 256;
    const bf16* W = isaux ? (WhCb + (size_t)l * 768 * 768) : (WhFIO + (size_t)l * 768 * 256);
    const int ldw = isaux ? 768 : 256;
    bf16* C = (isaux ? auxb : hgb) + (size_t)l * 4096 * 768;
    const bool do_g = isaux && (blockIdx.x == 0);

    const int m0 = blockIdx.y * BM;
    const int n0 = blockIdx.x * BN;
    const int tid  = threadIdx.x;
    const int lane = tid & 63;
    const int wave = tid >> 6;
    const int wm = (wave >> 1) * 64;
    const int wn = (wave & 1) * 64;
    const int q   = lane >> 4;
    const int r16 = lane & 15;

    f32x4 acc[4][4] = {};
    f32x4 accg[4] = {};

    const int trow = tid >> 3;
    const int tcol = (tid & 7) * 8;

    uint4 ra[4], rb[4], rg;
    #pragma unroll
    for (int p = 0; p < 4; ++p) {
        ra[p] = *(const uint4*)(A + (size_t)(m0 + p * 32 + trow) * 768 + tcol);
        rb[p] = *(const uint4*)(W + (size_t)(n0 + p * 32 + trow) * ldw + tcol);
    }
    if (do_g && tid < 128)
        rg = *(const uint4*)(WgH + (size_t)l * 16 * 768 + (size_t)(tid >> 3) * 768 + tcol);

    for (int k0 = 0; k0 < K; k0 += BK) {
        if (k0) __syncthreads();
        #pragma unroll
        for (int p = 0; p < 4; ++p) {
            *(uint4*)&As[(p * 32 + trow) * SK + tcol] = ra[p];
            *(uint4*)&Bs[(p * 32 + trow) * SK + tcol] = rb[p];
        }
        if (do_g && tid < 128)
            *(uint4*)&Bg[(tid >> 3) * SK + tcol] = rg;
        __syncthreads();
        if (k0 + BK < K) {
            #pragma unroll
            for (int p = 0; p < 4; ++p) {
                ra[p] = *(const uint4*)(A + (size_t)(m0 + p * 32 + trow) * 768 + k0 + BK + tcol);
                rb[p] = *(const uint4*)(W + (size_t)(n0 + p * 32 + trow) * ldw + k0 + BK + tcol);
            }
            if (do_g && tid < 128)
                rg = *(const uint4*)(WgH + (size_t)l * 16 * 768 + (size_t)(tid >> 3) * 768
                                     + k0 + BK + tcol);
        }
        #pragma unroll
        for (int kk = 0; kk < 2; ++kk) {
            const int ko = kk * 32 + q * 8;
            frag8 af[4], bfr[4];
            #pragma unroll
            for (int i = 0; i < 4; ++i)
                af[i] = *(const frag8*)&As[(wm + i * 16 + r16) * SK + ko];
            #pragma unroll
            for (int j = 0; j < 4; ++j)
                bfr[j] = *(const frag8*)&Bs[(wn + j * 16 + r16) * SK + ko];
            #pragma unroll
            for (int i = 0; i < 4; ++i)
                #pragma unroll
                for (int j = 0; j < 4; ++j)
                    acc[i][j] = __builtin_amdgcn_mfma_f32_16x16x32_bf16(
                        af[i], bfr[j], acc[i][j], 0, 0, 0);
            if (do_g) {
                frag8 bg = *(const frag8*)&Bg[r16 * SK + ko];
                #pragma unroll
                for (int i = 0; i < 4; ++i)
                    accg[i] = __builtin_amdgcn_mfma_f32_16x16x32_bf16(
                        af[i], bg, accg[i], 0, 0, 0);
            }
        }
    }

    // C store (bf16)
    #pragma unroll
    for (int i = 0; i < 4; ++i)
        #pragma unroll
        for (int rr = 0; rr < 4; ++rr) {
            int row = m0 + wm + i * 16 + q * 4 + rr;
            bf16* crow = C + (size_t)row * 768 + n0 + wn + r16;
            #pragma unroll
            for (int j = 0; j < 4; ++j) crow[j * 16] = __float2bfloat16(acc[i][j][rr]);
        }
    // gh store (pre-sigmoid, biases folded): wn==0 waves, lanes r16<3
    if (do_g && wn == 0 && r16 < 3) {
        float bsum = big[l * 3 + r16] + bhg[l * 3 + r16];
        #pragma unroll
        for (int i = 0; i < 4; ++i)
            #pragma unroll
            for (int rr = 0; rr < 4; ++rr) {
                int row = m0 + wm + i * 16 + q * 4 + rr;
                gh[(size_t)row * 9 + l * 3 + r16] = accg[i][rr] + bsum;
            }
    }
}

// ---------------- fused input-GEMM + gates (layers 1,2) ----------------
// A [4096 x 256] bf16 (lda=768 col-slice), Wi interleaved [1024][256] (n=4j+gate, f,i,o,c),
// Wg [16][256] rows 0..2 = Wi_g[l]. Grid (8, 32), block 256.
struct Stage { short As[BM * SK]; short Bs[BN * SK]; short Bg[16 * SK]; };
union SMemU { Stage s; float ct[64 * 128]; };

__global__ __launch_bounds__(256, 2)
void gemm_gates(const bf16* __restrict__ A, int lda,
                const bf16* __restrict__ Wi, const bf16* __restrict__ Wg,
                const bf16* __restrict__ hg_l,   // [4096][768] bf16
                const bf16* __restrict__ aux_l,  // [4096][768] bf16
                const float* __restrict__ ghc_l, // gh + l*3, stride 9, biases folded
                const float* __restrict__ cprev,
                const float* __restrict__ bif, const float* __restrict__ bhf,
                const float* __restrict__ bii, const float* __restrict__ bhi,
                const float* __restrict__ bio, const float* __restrict__ bho,
                const float* __restrict__ bic, const float* __restrict__ bhc, // [768]
                bf16*  __restrict__ hnew,   // col-slice base, row stride 768
                float* __restrict__ cnew,
                bf16*  __restrict__ featc)  // nullable, row stride 2304
{
    __shared__ SMemU sm;
    __shared__ float gsh[128 * 3];

    const int m0 = blockIdx.y * BM;
    const int n0 = blockIdx.x * BN;
    const int jbase = n0 >> 2;
    const int tid  = threadIdx.x;
    const int lane = tid & 63;
    const int wave = tid >> 6;
    const int wm = (wave >> 1) * 64;
    const int wn = (wave & 1) * 64;
    const int q   = lane >> 4;
    const int r16 = lane & 15;

    f32x4 acc[4][4] = {};
    f32x4 accg[4] = {};

    const int trow = tid >> 3;
    const int tcol = (tid & 7) * 8;

    uint4 ra[4], rb[4], rg;
    #pragma unroll
    for (int p = 0; p < 4; ++p) {
        ra[p] = *(const uint4*)(A + (size_t)(m0 + p * 32 + trow) * lda + tcol);
        rb[p] = *(const uint4*)(Wi + (size_t)(n0 + p * 32 + trow) * 256 + tcol);
    }
    if (tid < 128)
        rg = *(const uint4*)(Wg + (size_t)(tid >> 3) * 256 + tcol);

    for (int k0 = 0; k0 < 256; k0 += BK) {
        if (k0) __syncthreads();
        #pragma unroll
        for (int p = 0; p < 4; ++p) {
            *(uint4*)&sm.s.As[(p * 32 + trow) * SK + tcol] = ra[p];
            *(uint4*)&sm.s.Bs[(p * 32 + trow) * SK + tcol] = rb[p];
        }
        if (tid < 128)
            *(uint4*)&sm.s.Bg[(tid >> 3) * SK + tcol] = rg;
        __syncthreads();
        if (k0 + BK < 256) {
            #pragma unroll
            for (int p = 0; p < 4; ++p) {
                ra[p] = *(const uint4*)(A + (size_t)(m0 + p * 32 + trow) * lda + k0 + BK + tcol);
                rb[p] = *(const uint4*)(Wi + (size_t)(n0 + p * 32 + trow) * 256 + k0 + BK + tcol);
            }
            if (tid < 128)
                rg = *(const uint4*)(Wg + (size_t)(tid >> 3) * 256 + k0 + BK + tcol);
        }
        #pragma unroll
        for (int kk = 0; kk < 2; ++kk) {
            const int ko = kk * 32 + q * 8;
            frag8 af[4], bfr[4], bg;
            bg = *(const frag8*)&sm.s.Bg[r16 * SK + ko];
            #pragma unroll
            for (int i = 0; i < 4; ++i)
                af[i] = *(const frag8*)&sm.s.As[(wm + i * 16 + r16) * SK + ko];
            #pragma unroll
            for (int j = 0; j < 4; ++j)
                bfr[j] = *(const frag8*)&sm.s.Bs[(wn + j * 16 + r16) * SK + ko];
            #pragma unroll
            for (int i = 0; i < 4; ++i) {
                #pragma unroll
                for (int j = 0; j < 4; ++j)
                    acc[i][j] = __builtin_amdgcn_mfma_f32_16x16x32_bf16(
                        af[i], bfr[j], acc[i][j], 0, 0, 0);
                accg[i] = __builtin_amdgcn_mfma_f32_16x16x32_bf16(
                    af[i], bg, accg[i], 0, 0, 0);
            }
        }
    }

    __syncthreads();   // staging reads done; sm union becomes ct
    if (wn == 0 && r16 < 3) {
        #pragma unroll
        for (int i = 0; i < 4; ++i)
            #pragma unroll
            for (int rr = 0; rr < 4; ++rr) {
                int row = wm + i * 16 + q * 4 + rr;
                gsh[row * 3 + r16] = sigm(accg[i][rr] + ghc_l[(size_t)(m0 + row) * 9 + r16]);
            }
    }

    const int jj = tid & 31;
    const int r0 = (tid >> 5) * 8;
    const int j  = jbase + jj;
    const float vbif = bif[j], vbhf = bhf[j];
    const float vbii = bii[j], vbhi = bhi[j];
    const float vbio = bio[j], vbho = bho[j];
    const float vbic = bic[j];
    const float vbc0 = bhc[j], vbc1 = bhc[256 + j], vbc2 = bhc[512 + j];

    #pragma unroll
    for (int pass = 0; pass < 2; ++pass) {
        __syncthreads();
        if ((wave >> 1) == pass) {
            #pragma unroll
            for (int i = 0; i < 4; ++i)
                #pragma unroll
                for (int rr = 0; rr < 4; ++rr) {
                    int rowl = i * 16 + q * 4 + rr;
                    #pragma unroll
                    for (int jr = 0; jr < 4; ++jr) {
                        int col = wn + jr * 16 + r16;
                        sm.ct[rowl * 128 + ((col + 4 * rowl) & 127)] = acc[i][jr][rr];
                    }
                }
        }
        __syncthreads();
        for (int ri = 0; ri < 8; ++ri) {
            int rowl = r0 + ri;
            int rowg = pass * 64 + rowl;
            size_t b = m0 + rowg;
            float4 pre = *(float4*)&sm.ct[rowl * 128 + ((4 * jj + 4 * rowl) & 127)];
            float g0 = gsh[rowg * 3 + 0];
            float g1 = gsh[rowg * 3 + 1];
            float g2 = gsh[rowg * 3 + 2];
            float hgf = __bfloat162float(hg_l[b * 768 + j]);
            float hgi = __bfloat162float(hg_l[b * 768 + 256 + j]);
            float hgo = __bfloat162float(hg_l[b * 768 + 512 + j]);
            float ax0 = __bfloat162float(aux_l[b * 768 + j]);
            float ax1 = __bfloat162float(aux_l[b * 768 + 256 + j]);
            float ax2 = __bfloat162float(aux_l[b * 768 + 512 + j]);
            float f  = sigm(pre.x + vbif + hgf + vbhf);
            float ii = sigm(pre.y + vbii + hgi + vbhi);
            float o  = sigm(pre.z + vbio + hgo + vbho);
            float av = g0 * (ax0 + vbc0) + g1 * (ax1 + vbc1) + g2 * (ax2 + vbc2);
            float ct = tanhf(pre.w + vbic + av);
            float c  = f * cprev[b * 256 + j] + ii * ct;
            float h  = o * c;
            cnew[b * 256 + j] = c;
            hnew[b * 768 + j] = __float2bfloat16(h);
            if (featc) featc[b * 2304 + j] = __float2bfloat16(h);
        }
    }
}

// ---------------- layer-0 gates from precomputed pre-acts ----------------
__global__ __launch_bounds__(256)
void gates_pre(const bf16* __restrict__ ipre0i, const float* __restrict__ gin0,
               const float* __restrict__ ghc,
               const bf16* __restrict__ hg_l, const bf16* __restrict__ aux_l,
               const float* __restrict__ cprev,
               const float* __restrict__ bif, const float* __restrict__ bhf,
               const float* __restrict__ bii, const float* __restrict__ bhi,
               const float* __restrict__ bio, const float* __restrict__ bho,
               const float* __restrict__ bic, const float* __restrict__ bhc,
               bf16* __restrict__ hnew, float* __restrict__ cnew)
{
    const int j = threadIdx.x;
    const int b0 = blockIdx.x * 16;
    const float vbif = bif[j], vbhf = bhf[j];
    const float vbii = bii[j], vbhi = bhi[j];
    const float vbio = bio[j], vbho = bho[j];
    const float vbic = bic[j];
    const float vbc0 = bhc[j], vbc1 = bhc[256 + j], vbc2 = bhc[512 + j];

    for (int r = 0; r < 16; ++r) {
        const size_t b = b0 + r;
        const bf16* ip4 = ipre0i + b * 1024 + 4 * j;
        float pf = __bfloat162float(ip4[0]);
        float pi = __bfloat162float(ip4[1]);
        float po = __bfloat162float(ip4[2]);
        float pc = __bfloat162float(ip4[3]);
        float g0 = sigm(gin0[b * 3 + 0] + ghc[b * 9 + 0]);
        float g1 = sigm(gin0[b * 3 + 1] + ghc[b * 9 + 1]);
        float g2 = sigm(gin0[b * 3 + 2] + ghc[b * 9 + 2]);
        float hgf = __bfloat162float(hg_l[b * 768 + j]);
        float hgi = __bfloat162float(hg_l[b * 768 + 256 + j]);
        float hgo = __bfloat162float(hg_l[b * 768 + 512 + j]);
        float ax0 = __bfloat162float(aux_l[b * 768 + j]);
        float ax1 = __bfloat162float(aux_l[b * 768 + 256 + j]);
        float ax2 = __bfloat162float(aux_l[b * 768 + 512 + j]);
        float f  = sigm(pf + vbif + hgf + vbhf);
        float ii = sigm(pi + vbii + hgi + vbhi);
        float o  = sigm(po + vbio + hgo + vbho);
        float av = g0 * (ax0 + vbc0) + g1 * (ax1 + vbc1) + g2 * (ax2 + vbc2);
        float ct = tanhf(pc + vbic + av);
        float c  = f * cprev[b * 256 + j] + ii * ct;
        float h  = o * c;
        cnew[b * 256 + j] = c;
        hnew[b * 768 + j] = __float2bfloat16(h);
    }
}

// gin0[b][s] = xb[b,:] . Wi_g[0][s][:]  (no bias; constant over t)
__global__ __launch_bounds__(256)
void gin0_kernel(const bf16* __restrict__ xb, const float* __restrict__ Wig,
                 float* __restrict__ gout)
{
    const int wave = threadIdx.x >> 6, lane = threadIdx.x & 63;
    for (int rep = 0; rep < 4; ++rep) {
        size_t b = (size_t)blockIdx.x * 16 + wave * 4 + rep;
        float hv[4];
        #pragma unroll
        for (int m = 0; m < 4; ++m)
            hv[m] = __bfloat162float(xb[b * 256 + m * 64 + lane]);
        float p[3];
        #pragma unroll
        for (int s = 0; s < 3; ++s) {
            float t = 0.f;
            const float* w = Wig + (size_t)s * 256;
            #pragma unroll
            for (int m = 0; m < 4; ++m) t += hv[m] * w[m * 64 + lane];
            p[s] = t;
        }
        #pragma unroll
        for (int off = 32; off; off >>= 1)
            #pragma unroll
            for (int s = 0; s < 3; ++s) p[s] += __shfl_down(p[s], off);
        if (lane == 0) {
            #pragma unroll
            for (int s = 0; s < 3; ++s) gout[b * 3 + s] = p[s];
        }
    }
}

// out[b][n] = sigm(bias[n] + sum_z part[z][b][n]), n<44
__global__ __launch_bounds__(256)
void final_reduce(const float* __restrict__ part, const float* __restrict__ bl,
                  float* __restrict__ out)
{
    int idx = blockIdx.x * 256 + threadIdx.x;
    if (idx >= 4096 * 44) return;
    int b = idx / 44, n = idx - b * 44;
    float s = bl[n];
    #pragma unroll
    for (int z = 0; z < 12; ++z) s += part[(size_t)z * 4096 * 64 + (size_t)b * 64 + n];
    out[idx] = sigm(s);
}

// ---------------- prep kernels ----------------
__global__ void build_wicati(const float* __restrict__ Wf, const float* __restrict__ Wi,
                             const float* __restrict__ Wo, const float* __restrict__ Wc,
                             bf16* __restrict__ out)
{
    int idx = blockIdx.x * 256 + threadIdx.x;  // 3*1024*256
    int k = idx & 255, n = (idx >> 8) & 1023, l = idx >> 18;
    int j = n >> 2, g = n & 3;
    const float* src = (g == 0) ? Wf : (g == 1) ? Wi : (g == 2) ? Wo : Wc;
    out[idx] = __float2bfloat16(src[l * 65536 + j * 256 + k]);
}

__global__ void build_whfio(const float* __restrict__ Wf, const float* __restrict__ Wi,
                            const float* __restrict__ Wo, bf16* __restrict__ out)
{
    int idx = blockIdx.x * 256 + threadIdx.x;  // 3*768*256
    int k = idx & 255, n = (idx >> 8) % 768, l = idx / 196608;
    const float* src = (n < 256) ? Wf : (n < 512) ? Wi : Wo;
    out[idx] = __float2bfloat16(src[l * 65536 + (n & 255) * 256 + k]);
}

__global__ void build_wg(const float* __restrict__ Wig, bf16* __restrict__ out)
{
    int idx = blockIdx.x * 256 + threadIdx.x;  // 3*16*256
    int k = idx & 255, r = (idx >> 8) & 15, l = idx >> 12;
    out[idx] = (r < 3) ? __float2bfloat16(Wig[l * 768 + r * 256 + k]) : __float2bfloat16(0.f);
}

// WgH [3][16][768]: rows 0..2 = Wh_g[l] ([3][3][768]), rest zero
__global__ void build_wgh(const float* __restrict__ Whg, bf16* __restrict__ out)
{
    int idx = blockIdx.x * 256 + threadIdx.x;  // 3*16*768
    int k = idx % 768, r = (idx / 768) & 15, l = idx / (16 * 768);
    out[idx] = (r < 3) ? __float2bfloat16(Whg[(l * 3 + r) * 768 + k]) : __float2bfloat16(0.f);
}

__global__ void build_wlast(const float* __restrict__ Wl, bf16* __restrict__ out)
{
    int idx = blockIdx.x * 256 + threadIdx.x;  // 128*2304
    int k = idx % 2304, n = idx / 2304;
    out[idx] = (n < 44) ? __float2bfloat16(Wl[n * 2304 + k]) : __float2bfloat16(0.f);
}

__global__ void convert_f2b(const float* __restrict__ in, bf16* __restrict__ out, int n)
{
    int idx = blockIdx.x * 256 + threadIdx.x;
    if (idx < n) out[idx] = __float2bfloat16(in[idx]);
}

__global__ void init_state(const float* __restrict__ hidden0, const float* __restrict__ current0,
                           bf16* __restrict__ hcat, float* __restrict__ c0)
{
    int idx = blockIdx.x * 256 + threadIdx.x;  // 3*4096*256
    int j = idx & 255, b = (idx >> 8) & 4095, l = idx >> 20;
    hcat[(size_t)b * 768 + l * 256 + j] = __float2bfloat16(hidden0[idx]);
    c0[idx] = current0[idx];
}

extern "C" void kernel_launch(void* const* d_in, const int* in_sizes, int n_in,
                              void* d_out, int out_size, void* d_ws, size_t ws_size,
                              hipStream_t stream)
{
    (void)in_sizes; (void)n_in; (void)out_size; (void)ws_size;
    const float* x        = (const float*)d_in[0];
    const float* hidden0  = (const float*)d_in[1];
    const float* current0 = (const float*)d_in[2];
    const float* Wi_f = (const float*)d_in[3];  const float* bi_f = (const float*)d_in[4];
    const float* Wi_i = (const float*)d_in[5];  const float* bi_i = (const float*)d_in[6];
    const float* Wi_o = (const float*)d_in[7];  const float* bi_o = (const float*)d_in[8];
    const float* Wi_c = (const float*)d_in[9];  const float* bi_c = (const float*)d_in[10];
    const float* Wi_g = (const float*)d_in[11]; const float* bi_g = (const float*)d_in[12];
    const float* Wh_f = (const float*)d_in[13]; const float* bh_f = (const float*)d_in[14];
    const float* Wh_i = (const float*)d_in[15]; const float* bh_i = (const float*)d_in[16];
    const float* Wh_o = (const float*)d_in[17]; const float* bh_o = (const float*)d_in[18];
    const float* Wh_g = (const float*)d_in[19]; const float* bh_g = (const float*)d_in[20];
    const float* Wh_c = (const float*)d_in[21]; const float* bh_c = (const float*)d_in[22];
    const float* W_last = (const float*)d_in[23]; const float* b_last = (const float*)d_in[24];

    char* p = (char*)d_ws;
    bf16* WiCatI = (bf16*)p; p += (size_t)3 * 1024 * 256 * 2;
    bf16* WhFIO  = (bf16*)p; p += (size_t)3 * 768 * 256 * 2;
    bf16* WhCb   = (bf16*)p; p += (size_t)3 * 768 * 768 * 2;
    bf16* Wgb    = (bf16*)p; p += (size_t)3 * 16 * 256 * 2;
    bf16* WgH    = (bf16*)p; p += (size_t)3 * 16 * 768 * 2;
    bf16* Wlb    = (bf16*)p; p += (size_t)128 * 2304 * 2;
    bf16* xb     = (bf16*)p; p += (size_t)4096 * 256 * 2;
    bf16* ipre0i = (bf16*)p; p += (size_t)4096 * 1024 * 2;
    float* gin0  = (float*)p; p += (size_t)4096 * 3 * 4;
    bf16* hb0    = (bf16*)p; p += (size_t)4096 * 768 * 2;
    bf16* hb1    = (bf16*)p; p += (size_t)4096 * 768 * 2;
    float* cb0   = (float*)p; p += (size_t)3 * 4096 * 256 * 4;
    float* cb1   = (float*)p; p += (size_t)3 * 4096 * 256 * 4;
    bf16* hgb    = (bf16*)p; p += (size_t)3 * 4096 * 768 * 2;
    bf16* auxb   = (bf16*)p; p += (size_t)3 * 4096 * 768 * 2;
    float* gh    = (float*)p; p += (size_t)4096 * 9 * 4;
    bf16* feat   = (bf16*)p; p += (size_t)4096 * 2304 * 2;
    float* partf = (float*)p; p += (size_t)12 * 4096 * 64 * 4;

    build_wicati<<<3072, 256, 0, stream>>>(Wi_f, Wi_i, Wi_o, Wi_c, WiCatI);
    build_whfio<<<2304, 256, 0, stream>>>(Wh_f, Wh_i, Wh_o, WhFIO);
    convert_f2b<<<(3 * 768 * 768 + 255) / 256, 256, 0, stream>>>(Wh_c, WhCb, 3 * 768 * 768);
    build_wg<<<48, 256, 0, stream>>>(Wi_g, Wgb);
    build_wgh<<<144, 256, 0, stream>>>(Wh_g, WgH);
    build_wlast<<<1152, 256, 0, stream>>>(W_last, Wlb);
    convert_f2b<<<4096, 256, 0, stream>>>(x, xb, 4096 * 256);
    init_state<<<12288, 256, 0, stream>>>(hidden0, current0, hb0, cb0);

    // hoisted layer-0 input-side work (x constant across t)
    gemm_bt<<<dim3(8, 32, 1), 256, 0, stream>>>(xb, 256, 0, WiCatI, 256, 0,
                                                ipre0i, 1024, 0, 256, 1, nullptr, 0);
    gin0_kernel<<<256, 256, 0, stream>>>(xb, Wi_g, gin0);

    for (int t = 0; t < 10; ++t) {
        bf16* hprev = (t & 1) ? hb1 : hb0;
        bf16* hnew  = (t & 1) ? hb0 : hb1;
        float* cprev = (t & 1) ? cb1 : cb0;
        float* cnew  = (t & 1) ? cb0 : cb1;

        // hg (z<3) + aux (z>=3) + gh, one launch
        gemm_hidden<<<dim3(6, 32, 6), 256, 0, stream>>>(
            hprev, WhFIO, WhCb, WgH, bi_g, bh_g, hgb, auxb, gh);

        gates_pre<<<256, 256, 0, stream>>>(
            ipre0i, gin0, gh,
            hgb, auxb, cprev,
            bi_f, bh_f, bi_i, bh_i, bi_o, bh_o, bi_c, bh_c,
            hnew, cnew);

        for (int l = 1; l < 3; ++l) {
            gemm_gates<<<dim3(8, 32), 256, 0, stream>>>(
                (const bf16*)(hnew + (l - 1) * 256), 768,
                WiCatI + (size_t)l * 1024 * 256,
                Wgb + (size_t)l * 16 * 256,
                hgb + (size_t)l * 4096 * 768,
                auxb + (size_t)l * 4096 * 768,
                gh + l * 3,
                cprev + (size_t)l * 4096 * 256,
                bi_f + l * 256, bh_f + l * 256,
                bi_i + l * 256, bh_i + l * 256,
                bi_o + l * 256, bh_o + l * 256,
                bi_c + l * 256, bh_c + l * 768,
                hnew + l * 256,
                cnew + (size_t)l * 4096 * 256,
                (l == 2 && t < 9) ? (feat + (size_t)t * 256) : (bf16*)nullptr);
        }
    }

    // final: K-split feat[4096,2304] @ Wlb[128,2304]^T into 12 partials of K=192
    gemm_bt<<<dim3(1, 32, 12), 256, 0, stream>>>(
        feat, 2304, 192, Wlb, 2304, 192,
        partf, 64, (long long)4096 * 64, 192, 3, nullptr, 64);
    final_reduce<<<704, 256, 0, stream>>>(partf, b_last, (float*)d_out);
}

// Round 7
// 1412.093 us; speedup vs baseline: 1.6452x; 1.4217x over previous
//
#include <hip/hip_runtime.h>
#include <hip/hip_bf16.h>

typedef __hip_bfloat16 bf16;
typedef __attribute__((ext_vector_type(8))) short frag8;   // 8 bf16 = 4 VGPRs
typedef __attribute__((ext_vector_type(4))) float f32x4;

#define BM 128
#define BN 128
#define BK 64
#define SK 72   // padded LDS row stride: 2-way max bank aliasing on staging AND fragment reads

__device__ __forceinline__ float sigm(float x) { return 1.f / (1.f + __expf(-x)); }

// C[m,n] = sum_k A[m,k] * W[n,k]; A [M,K] bf16 (lda), W [N,K] bf16 (ldw). 128x128 tile.
// In-loop staging (NO register prefetch: r5/r6 showed that pattern spills ~200MB scratch).
// outmode: 0 fp32, 1 bf16, 2 sigmoid(acc+bias[n]) fp32 n<nbound, 3 raw fp32 n<nbound.
__global__ __launch_bounds__(256, 2)
void gemm_bt(const bf16* __restrict__ A, int lda, long long sAz,
             const bf16* __restrict__ W, int ldw, long long sWz,
             void* __restrict__ Cv, int ldc, long long sCz, int K,
             int outmode, const float* __restrict__ bias, int nbound)
{
    __shared__ short As[BM * SK];
    __shared__ short Bs[BN * SK];
    const int z = blockIdx.z;
    A += (size_t)z * sAz;
    W += (size_t)z * sWz;
    const int m0 = blockIdx.y * BM;
    const int n0 = blockIdx.x * BN;
    const int tid  = threadIdx.x;
    const int lane = tid & 63;
    const int wave = tid >> 6;
    const int wm = (wave >> 1) * 64;
    const int wn = (wave & 1) * 64;
    const int q   = lane >> 4;
    const int r16 = lane & 15;

    f32x4 acc[4][4] = {};

    const int trow = tid >> 3;         // 0..31
    const int tcol = (tid & 7) * 8;    // 16B chunk (bf16 elems)

    for (int k0 = 0; k0 < K; k0 += BK) {
        __syncthreads();
        #pragma unroll
        for (int p = 0; p < 4; ++p) {
            int rr = p * 32 + trow;
            *(uint4*)&As[rr * SK + tcol] =
                *(const uint4*)(A + (size_t)(m0 + rr) * lda + k0 + tcol);
            *(uint4*)&Bs[rr * SK + tcol] =
                *(const uint4*)(W + (size_t)(n0 + rr) * ldw + k0 + tcol);
        }
        __syncthreads();
        #pragma unroll
        for (int kk = 0; kk < 2; ++kk) {
            const int ko = kk * 32 + q * 8;
            frag8 af[4], bfr[4];
            #pragma unroll
            for (int i = 0; i < 4; ++i)
                af[i] = *(const frag8*)&As[(wm + i * 16 + r16) * SK + ko];
            #pragma unroll
            for (int j = 0; j < 4; ++j)
                bfr[j] = *(const frag8*)&Bs[(wn + j * 16 + r16) * SK + ko];
            #pragma unroll
            for (int i = 0; i < 4; ++i)
                #pragma unroll
                for (int j = 0; j < 4; ++j)
                    acc[i][j] = __builtin_amdgcn_mfma_f32_16x16x32_bf16(
                        af[i], bfr[j], acc[i][j], 0, 0, 0);
        }
    }

    // C/D layout: col = lane&15 (+16j+wn), row = (lane>>4)*4 + reg (+16i+wm)
    if (outmode == 0) {
        float* C = (float*)Cv + (size_t)z * sCz;
        #pragma unroll
        for (int i = 0; i < 4; ++i)
            #pragma unroll
            for (int rr = 0; rr < 4; ++rr) {
                int row = m0 + wm + i * 16 + q * 4 + rr;
                float* crow = C + (size_t)row * ldc + n0 + wn + r16;
                #pragma unroll
                for (int j = 0; j < 4; ++j) crow[j * 16] = acc[i][j][rr];
            }
    } else if (outmode == 1) {
        bf16* C = (bf16*)Cv + (size_t)z * sCz;
        #pragma unroll
        for (int i = 0; i < 4; ++i)
            #pragma unroll
            for (int rr = 0; rr < 4; ++rr) {
                int row = m0 + wm + i * 16 + q * 4 + rr;
                bf16* crow = C + (size_t)row * ldc + n0 + wn + r16;
                #pragma unroll
                for (int j = 0; j < 4; ++j) crow[j * 16] = __float2bfloat16(acc[i][j][rr]);
            }
    } else if (outmode == 2) {
        float* C = (float*)Cv + (size_t)z * sCz;
        #pragma unroll
        for (int i = 0; i < 4; ++i)
            #pragma unroll
            for (int rr = 0; rr < 4; ++rr) {
                int row = m0 + wm + i * 16 + q * 4 + rr;
                #pragma unroll
                for (int j = 0; j < 4; ++j) {
                    int col = n0 + wn + j * 16 + r16;
                    if (col < nbound)
                        C[(size_t)row * ldc + col] = sigm(acc[i][j][rr] + bias[col]);
                }
            }
    } else {
        float* C = (float*)Cv + (size_t)z * sCz;
        #pragma unroll
        for (int i = 0; i < 4; ++i)
            #pragma unroll
            for (int rr = 0; rr < 4; ++rr) {
                int row = m0 + wm + i * 16 + q * 4 + rr;
                #pragma unroll
                for (int j = 0; j < 4; ++j) {
                    int col = n0 + wn + j * 16 + r16;
                    if (col < nbound)
                        C[(size_t)row * ldc + col] = acc[i][j][rr];
                }
            }
    }
}

// ---------------- merged hidden-side kernel ----------------
// Grid (6, 32, 6). z<3: hg GEMM for layer z (A = hprev col-slice, K=256, W=WhFIO[z]).
// z>=3: aux GEMM for layer z-3 (A = full hcat, K=768, W=WhCb[l]); x==0 blocks also
// compute gh[b][l*3+s] = hcat . Wh_g[l][s] + bi_g + bh_g via a 16-row B-fragment.
__global__ __launch_bounds__(256, 2)
void gemm_hidden(const bf16* __restrict__ hprev,
                 const bf16* __restrict__ WhFIO,  // [3][768][256]
                 const bf16* __restrict__ WhCb,   // [3][768][768]
                 const bf16* __restrict__ WgH,    // [3][16][768], rows 0..2 = Wh_g[l]
                 const float* __restrict__ big, const float* __restrict__ bhg,  // [9]
                 bf16* __restrict__ hgb,          // [3][4096][768]
                 bf16* __restrict__ auxb,         // [3][4096][768]
                 float* __restrict__ gh)          // [4096][9]
{
    __shared__ short As[BM * SK];
    __shared__ short Bs[BN * SK];
    __shared__ short Bg[16 * SK];

    const int z = blockIdx.z;
    const bool isaux = z >= 3;
    const int l = isaux ? z - 3 : z;
    const bf16* A = hprev + (isaux ? 0 : l * 256);
    const int K = isaux ? 768 : 256;
    const bf16* W = isaux ? (WhCb + (size_t)l * 768 * 768) : (WhFIO + (size_t)l * 768 * 256);
    const int ldw = isaux ? 768 : 256;
    bf16* C = (isaux ? auxb : hgb) + (size_t)l * 4096 * 768;
    const bool do_g = isaux && (blockIdx.x == 0);

    const int m0 = blockIdx.y * BM;
    const int n0 = blockIdx.x * BN;
    const int tid  = threadIdx.x;
    const int lane = tid & 63;
    const int wave = tid >> 6;
    const int wm = (wave >> 1) * 64;
    const int wn = (wave & 1) * 64;
    const int q   = lane >> 4;
    const int r16 = lane & 15;

    f32x4 acc[4][4] = {};
    f32x4 accg[4] = {};

    const int trow = tid >> 3;
    const int tcol = (tid & 7) * 8;
    const bf16* WgL = WgH + (size_t)l * 16 * 768;

    for (int k0 = 0; k0 < K; k0 += BK) {
        __syncthreads();
        #pragma unroll
        for (int p = 0; p < 4; ++p) {
            int rr = p * 32 + trow;
            *(uint4*)&As[rr * SK + tcol] =
                *(const uint4*)(A + (size_t)(m0 + rr) * 768 + k0 + tcol);
            *(uint4*)&Bs[rr * SK + tcol] =
                *(const uint4*)(W + (size_t)(n0 + rr) * ldw + k0 + tcol);
        }
        if (do_g && tid < 128)
            *(uint4*)&Bg[(tid >> 3) * SK + tcol] =
                *(const uint4*)(WgL + (size_t)(tid >> 3) * 768 + k0 + tcol);
        __syncthreads();
        #pragma unroll
        for (int kk = 0; kk < 2; ++kk) {
            const int ko = kk * 32 + q * 8;
            frag8 af[4], bfr[4];
            #pragma unroll
            for (int i = 0; i < 4; ++i)
                af[i] = *(const frag8*)&As[(wm + i * 16 + r16) * SK + ko];
            #pragma unroll
            for (int j = 0; j < 4; ++j)
                bfr[j] = *(const frag8*)&Bs[(wn + j * 16 + r16) * SK + ko];
            #pragma unroll
            for (int i = 0; i < 4; ++i)
                #pragma unroll
                for (int j = 0; j < 4; ++j)
                    acc[i][j] = __builtin_amdgcn_mfma_f32_16x16x32_bf16(
                        af[i], bfr[j], acc[i][j], 0, 0, 0);
            if (do_g) {
                frag8 bg = *(const frag8*)&Bg[r16 * SK + ko];
                #pragma unroll
                for (int i = 0; i < 4; ++i)
                    accg[i] = __builtin_amdgcn_mfma_f32_16x16x32_bf16(
                        af[i], bg, accg[i], 0, 0, 0);
            }
        }
    }

    // C store (bf16)
    #pragma unroll
    for (int i = 0; i < 4; ++i)
        #pragma unroll
        for (int rr = 0; rr < 4; ++rr) {
            int row = m0 + wm + i * 16 + q * 4 + rr;
            bf16* crow = C + (size_t)row * 768 + n0 + wn + r16;
            #pragma unroll
            for (int j = 0; j < 4; ++j) crow[j * 16] = __float2bfloat16(acc[i][j][rr]);
        }
    // gh store (pre-sigmoid, biases folded): wn==0 waves, lanes r16<3
    if (do_g && wn == 0 && r16 < 3) {
        float bsum = big[l * 3 + r16] + bhg[l * 3 + r16];
        #pragma unroll
        for (int i = 0; i < 4; ++i)
            #pragma unroll
            for (int rr = 0; rr < 4; ++rr) {
                int row = m0 + wm + i * 16 + q * 4 + rr;
                gh[(size_t)row * 9 + l * 3 + r16] = accg[i][rr] + bsum;
            }
    }
}

// ---------------- fused input-GEMM + gates (layers 1,2) ----------------
// A [4096 x 256] bf16 (lda=768 col-slice), Wi interleaved [1024][256] (n=4j+gate, f,i,o,c),
// Wg [16][256] rows 0..2 = Wi_g[l]. Grid (8, 32), block 256.
struct Stage { short As[BM * SK]; short Bs[BN * SK]; short Bg[16 * SK]; };
union SMemU { Stage s; float ct[64 * 128]; };

__global__ __launch_bounds__(256, 2)
void gemm_gates(const bf16* __restrict__ A, int lda,
                const bf16* __restrict__ Wi, const bf16* __restrict__ Wg,
                const bf16* __restrict__ hg_l,   // [4096][768] bf16
                const bf16* __restrict__ aux_l,  // [4096][768] bf16
                const float* __restrict__ ghc_l, // gh + l*3, stride 9, biases folded
                const float* __restrict__ cprev,
                const float* __restrict__ bif, const float* __restrict__ bhf,
                const float* __restrict__ bii, const float* __restrict__ bhi,
                const float* __restrict__ bio, const float* __restrict__ bho,
                const float* __restrict__ bic, const float* __restrict__ bhc, // [768]
                bf16*  __restrict__ hnew,   // col-slice base, row stride 768
                float* __restrict__ cnew,
                bf16*  __restrict__ featc)  // nullable, row stride 2304
{
    __shared__ SMemU sm;
    __shared__ float gsh[128 * 3];

    const int m0 = blockIdx.y * BM;
    const int n0 = blockIdx.x * BN;
    const int jbase = n0 >> 2;
    const int tid  = threadIdx.x;
    const int lane = tid & 63;
    const int wave = tid >> 6;
    const int wm = (wave >> 1) * 64;
    const int wn = (wave & 1) * 64;
    const int q   = lane >> 4;
    const int r16 = lane & 15;

    f32x4 acc[4][4] = {};
    f32x4 accg[4] = {};

    const int trow = tid >> 3;
    const int tcol = (tid & 7) * 8;

    for (int k0 = 0; k0 < 256; k0 += BK) {
        __syncthreads();
        #pragma unroll
        for (int p = 0; p < 4; ++p) {
            int rr = p * 32 + trow;
            *(uint4*)&sm.s.As[rr * SK + tcol] =
                *(const uint4*)(A + (size_t)(m0 + rr) * lda + k0 + tcol);
            *(uint4*)&sm.s.Bs[rr * SK + tcol] =
                *(const uint4*)(Wi + (size_t)(n0 + rr) * 256 + k0 + tcol);
        }
        if (tid < 128)
            *(uint4*)&sm.s.Bg[(tid >> 3) * SK + tcol] =
                *(const uint4*)(Wg + (size_t)(tid >> 3) * 256 + k0 + tcol);
        __syncthreads();
        #pragma unroll
        for (int kk = 0; kk < 2; ++kk) {
            const int ko = kk * 32 + q * 8;
            frag8 af[4], bfr[4], bg;
            bg = *(const frag8*)&sm.s.Bg[r16 * SK + ko];
            #pragma unroll
            for (int i = 0; i < 4; ++i)
                af[i] = *(const frag8*)&sm.s.As[(wm + i * 16 + r16) * SK + ko];
            #pragma unroll
            for (int j = 0; j < 4; ++j)
                bfr[j] = *(const frag8*)&sm.s.Bs[(wn + j * 16 + r16) * SK + ko];
            #pragma unroll
            for (int i = 0; i < 4; ++i) {
                #pragma unroll
                for (int j = 0; j < 4; ++j)
                    acc[i][j] = __builtin_amdgcn_mfma_f32_16x16x32_bf16(
                        af[i], bfr[j], acc[i][j], 0, 0, 0);
                accg[i] = __builtin_amdgcn_mfma_f32_16x16x32_bf16(
                    af[i], bg, accg[i], 0, 0, 0);
            }
        }
    }

    __syncthreads();   // staging reads done; sm union becomes ct
    if (wn == 0 && r16 < 3) {
        #pragma unroll
        for (int i = 0; i < 4; ++i)
            #pragma unroll
            for (int rr = 0; rr < 4; ++rr) {
                int row = wm + i * 16 + q * 4 + rr;
                gsh[row * 3 + r16] = sigm(accg[i][rr] + ghc_l[(size_t)(m0 + row) * 9 + r16]);
            }
    }

    const int jj = tid & 31;
    const int r0 = (tid >> 5) * 8;
    const int j  = jbase + jj;
    const float vbif = bif[j], vbhf = bhf[j];
    const float vbii = bii[j], vbhi = bhi[j];
    const float vbio = bio[j], vbho = bho[j];
    const float vbic = bic[j];
    const float vbc0 = bhc[j], vbc1 = bhc[256 + j], vbc2 = bhc[512 + j];

    #pragma unroll
    for (int pass = 0; pass < 2; ++pass) {
        __syncthreads();
        if ((wave >> 1) == pass) {
            #pragma unroll
            for (int i = 0; i < 4; ++i)
                #pragma unroll
                for (int rr = 0; rr < 4; ++rr) {
                    int rowl = i * 16 + q * 4 + rr;
                    #pragma unroll
                    for (int jr = 0; jr < 4; ++jr) {
                        int col = wn + jr * 16 + r16;
                        sm.ct[rowl * 128 + ((col + 4 * rowl) & 127)] = acc[i][jr][rr];
                    }
                }
        }
        __syncthreads();
        for (int ri = 0; ri < 8; ++ri) {
            int rowl = r0 + ri;
            int rowg = pass * 64 + rowl;
            size_t b = m0 + rowg;
            float4 pre = *(float4*)&sm.ct[rowl * 128 + ((4 * jj + 4 * rowl) & 127)];
            float g0 = gsh[rowg * 3 + 0];
            float g1 = gsh[rowg * 3 + 1];
            float g2 = gsh[rowg * 3 + 2];
            float hgf = __bfloat162float(hg_l[b * 768 + j]);
            float hgi = __bfloat162float(hg_l[b * 768 + 256 + j]);
            float hgo = __bfloat162float(hg_l[b * 768 + 512 + j]);
            float ax0 = __bfloat162float(aux_l[b * 768 + j]);
            float ax1 = __bfloat162float(aux_l[b * 768 + 256 + j]);
            float ax2 = __bfloat162float(aux_l[b * 768 + 512 + j]);
            float f  = sigm(pre.x + vbif + hgf + vbhf);
            float ii = sigm(pre.y + vbii + hgi + vbhi);
            float o  = sigm(pre.z + vbio + hgo + vbho);
            float av = g0 * (ax0 + vbc0) + g1 * (ax1 + vbc1) + g2 * (ax2 + vbc2);
            float ct = tanhf(pre.w + vbic + av);
            float c  = f * cprev[b * 256 + j] + ii * ct;
            float h  = o * c;
            cnew[b * 256 + j] = c;
            hnew[b * 768 + j] = __float2bfloat16(h);
            if (featc) featc[b * 2304 + j] = __float2bfloat16(h);
        }
    }
}

// ---------------- layer-0 gates from precomputed pre-acts ----------------
__global__ __launch_bounds__(256)
void gates_pre(const bf16* __restrict__ ipre0i, const float* __restrict__ gin0,
               const float* __restrict__ ghc,
               const bf16* __restrict__ hg_l, const bf16* __restrict__ aux_l,
               const float* __restrict__ cprev,
               const float* __restrict__ bif, const float* __restrict__ bhf,
               const float* __restrict__ bii, const float* __restrict__ bhi,
               const float* __restrict__ bio, const float* __restrict__ bho,
               const float* __restrict__ bic, const float* __restrict__ bhc,
               bf16* __restrict__ hnew, float* __restrict__ cnew)
{
    const int j = threadIdx.x;
    const int b0 = blockIdx.x * 16;
    const float vbif = bif[j], vbhf = bhf[j];
    const float vbii = bii[j], vbhi = bhi[j];
    const float vbio = bio[j], vbho = bho[j];
    const float vbic = bic[j];
    const float vbc0 = bhc[j], vbc1 = bhc[256 + j], vbc2 = bhc[512 + j];

    for (int r = 0; r < 16; ++r) {
        const size_t b = b0 + r;
        const bf16* ip4 = ipre0i + b * 1024 + 4 * j;
        float pf = __bfloat162float(ip4[0]);
        float pi = __bfloat162float(ip4[1]);
        float po = __bfloat162float(ip4[2]);
        float pc = __bfloat162float(ip4[3]);
        float g0 = sigm(gin0[b * 3 + 0] + ghc[b * 9 + 0]);
        float g1 = sigm(gin0[b * 3 + 1] + ghc[b * 9 + 1]);
        float g2 = sigm(gin0[b * 3 + 2] + ghc[b * 9 + 2]);
        float hgf = __bfloat162float(hg_l[b * 768 + j]);
        float hgi = __bfloat162float(hg_l[b * 768 + 256 + j]);
        float hgo = __bfloat162float(hg_l[b * 768 + 512 + j]);
        float ax0 = __bfloat162float(aux_l[b * 768 + j]);
        float ax1 = __bfloat162float(aux_l[b * 768 + 256 + j]);
        float ax2 = __bfloat162float(aux_l[b * 768 + 512 + j]);
        float f  = sigm(pf + vbif + hgf + vbhf);
        float ii = sigm(pi + vbii + hgi + vbhi);
        float o  = sigm(po + vbio + hgo + vbho);
        float av = g0 * (ax0 + vbc0) + g1 * (ax1 + vbc1) + g2 * (ax2 + vbc2);
        float ct = tanhf(pc + vbic + av);
        float c  = f * cprev[b * 256 + j] + ii * ct;
        float h  = o * c;
        cnew[b * 256 + j] = c;
        hnew[b * 768 + j] = __float2bfloat16(h);
    }
}

// gin0[b][s] = xb[b,:] . Wi_g[0][s][:]  (no bias; constant over t)
__global__ __launch_bounds__(256)
void gin0_kernel(const bf16* __restrict__ xb, const float* __restrict__ Wig,
                 float* __restrict__ gout)
{
    const int wave = threadIdx.x >> 6, lane = threadIdx.x & 63;
    for (int rep = 0; rep < 4; ++rep) {
        size_t b = (size_t)blockIdx.x * 16 + wave * 4 + rep;
        float hv[4];
        #pragma unroll
        for (int m = 0; m < 4; ++m)
            hv[m] = __bfloat162float(xb[b * 256 + m * 64 + lane]);
        float p[3];
        #pragma unroll
        for (int s = 0; s < 3; ++s) {
            float t = 0.f;
            const float* w = Wig + (size_t)s * 256;
            #pragma unroll
            for (int m = 0; m < 4; ++m) t += hv[m] * w[m * 64 + lane];
            p[s] = t;
        }
        #pragma unroll
        for (int off = 32; off; off >>= 1)
            #pragma unroll
            for (int s = 0; s < 3; ++s) p[s] += __shfl_down(p[s], off);
        if (lane == 0) {
            #pragma unroll
            for (int s = 0; s < 3; ++s) gout[b * 3 + s] = p[s];
        }
    }
}

// out[b][n] = sigm(bias[n] + sum_z part[z][b][n]), n<44
__global__ __launch_bounds__(256)
void final_reduce(const float* __restrict__ part, const float* __restrict__ bl,
                  float* __restrict__ out)
{
    int idx = blockIdx.x * 256 + threadIdx.x;
    if (idx >= 4096 * 44) return;
    int b = idx / 44, n = idx - b * 44;
    float s = bl[n];
    #pragma unroll
    for (int z = 0; z < 12; ++z) s += part[(size_t)z * 4096 * 64 + (size_t)b * 64 + n];
    out[idx] = sigm(s);
}

// ---------------- prep kernels ----------------
__global__ void build_wicati(const float* __restrict__ Wf, const float* __restrict__ Wi,
                             const float* __restrict__ Wo, const float* __restrict__ Wc,
                             bf16* __restrict__ out)
{
    int idx = blockIdx.x * 256 + threadIdx.x;  // 3*1024*256
    int k = idx & 255, n = (idx >> 8) & 1023, l = idx >> 18;
    int j = n >> 2, g = n & 3;
    const float* src = (g == 0) ? Wf : (g == 1) ? Wi : (g == 2) ? Wo : Wc;
    out[idx] = __float2bfloat16(src[l * 65536 + j * 256 + k]);
}

__global__ void build_whfio(const float* __restrict__ Wf, const float* __restrict__ Wi,
                            const float* __restrict__ Wo, bf16* __restrict__ out)
{
    int idx = blockIdx.x * 256 + threadIdx.x;  // 3*768*256
    int k = idx & 255, n = (idx >> 8) % 768, l = idx / 196608;
    const float* src = (n < 256) ? Wf : (n < 512) ? Wi : Wo;
    out[idx] = __float2bfloat16(src[l * 65536 + (n & 255) * 256 + k]);
}

__global__ void build_wg(const float* __restrict__ Wig, bf16* __restrict__ out)
{
    int idx = blockIdx.x * 256 + threadIdx.x;  // 3*16*256
    int k = idx & 255, r = (idx >> 8) & 15, l = idx >> 12;
    out[idx] = (r < 3) ? __float2bfloat16(Wig[l * 768 + r * 256 + k]) : __float2bfloat16(0.f);
}

// WgH [3][16][768]: rows 0..2 = Wh_g[l] ([3][3][768]), rest zero
__global__ void build_wgh(const float* __restrict__ Whg, bf16* __restrict__ out)
{
    int idx = blockIdx.x * 256 + threadIdx.x;  // 3*16*768
    int k = idx % 768, r = (idx / 768) & 15, l = idx / (16 * 768);
    out[idx] = (r < 3) ? __float2bfloat16(Whg[(l * 3 + r) * 768 + k]) : __float2bfloat16(0.f);
}

__global__ void build_wlast(const float* __restrict__ Wl, bf16* __restrict__ out)
{
    int idx = blockIdx.x * 256 + threadIdx.x;  // 128*2304
    int k = idx % 2304, n = idx / 2304;
    out[idx] = (n < 44) ? __float2bfloat16(Wl[n * 2304 + k]) : __float2bfloat16(0.f);
}

__global__ void convert_f2b(const float* __restrict__ in, bf16* __restrict__ out, int n)
{
    int idx = blockIdx.x * 256 + threadIdx.x;
    if (idx < n) out[idx] = __float2bfloat16(in[idx]);
}

__global__ void init_state(const float* __restrict__ hidden0, const float* __restrict__ current0,
                           bf16* __restrict__ hcat, float* __restrict__ c0)
{
    int idx = blockIdx.x * 256 + threadIdx.x;  // 3*4096*256
    int j = idx & 255, b = (idx >> 8) & 4095, l = idx >> 20;
    hcat[(size_t)b * 768 + l * 256 + j] = __float2bfloat16(hidden0[idx]);
    c0[idx] = current0[idx];
}

extern "C" void kernel_launch(void* const* d_in, const int* in_sizes, int n_in,
                              void* d_out, int out_size, void* d_ws, size_t ws_size,
                              hipStream_t stream)
{
    (void)in_sizes; (void)n_in; (void)out_size; (void)ws_size;
    const float* x        = (const float*)d_in[0];
    const float* hidden0  = (const float*)d_in[1];
    const float* current0 = (const float*)d_in[2];
    const float* Wi_f = (const float*)d_in[3];  const float* bi_f = (const float*)d_in[4];
    const float* Wi_i = (const float*)d_in[5];  const float* bi_i = (const float*)d_in[6];
    const float* Wi_o = (const float*)d_in[7];  const float* bi_o = (const float*)d_in[8];
    const float* Wi_c = (const float*)d_in[9];  const float* bi_c = (const float*)d_in[10];
    const float* Wi_g = (const float*)d_in[11]; const float* bi_g = (const float*)d_in[12];
    const float* Wh_f = (const float*)d_in[13]; const float* bh_f = (const float*)d_in[14];
    const float* Wh_i = (const float*)d_in[15]; const float* bh_i = (const float*)d_in[16];
    const float* Wh_o = (const float*)d_in[17]; const float* bh_o = (const float*)d_in[18];
    const float* Wh_g = (const float*)d_in[19]; const float* bh_g = (const float*)d_in[20];
    const float* Wh_c = (const float*)d_in[21]; const float* bh_c = (const float*)d_in[22];
    const float* W_last = (const float*)d_in[23]; const float* b_last = (const float*)d_in[24];

    char* p = (char*)d_ws;
    bf16* WiCatI = (bf16*)p; p += (size_t)3 * 1024 * 256 * 2;
    bf16* WhFIO  = (bf16*)p; p += (size_t)3 * 768 * 256 * 2;
    bf16* WhCb   = (bf16*)p; p += (size_t)3 * 768 * 768 * 2;
    bf16* Wgb    = (bf16*)p; p += (size_t)3 * 16 * 256 * 2;
    bf16* WgH    = (bf16*)p; p += (size_t)3 * 16 * 768 * 2;
    bf16* Wlb    = (bf16*)p; p += (size_t)128 * 2304 * 2;
    bf16* xb     = (bf16*)p; p += (size_t)4096 * 256 * 2;
    bf16* ipre0i = (bf16*)p; p += (size_t)4096 * 1024 * 2;
    float* gin0  = (float*)p; p += (size_t)4096 * 3 * 4;
    bf16* hb0    = (bf16*)p; p += (size_t)4096 * 768 * 2;
    bf16* hb1    = (bf16*)p; p += (size_t)4096 * 768 * 2;
    float* cb0   = (float*)p; p += (size_t)3 * 4096 * 256 * 4;
    float* cb1   = (float*)p; p += (size_t)3 * 4096 * 256 * 4;
    bf16* hgb    = (bf16*)p; p += (size_t)3 * 4096 * 768 * 2;
    bf16* auxb   = (bf16*)p; p += (size_t)3 * 4096 * 768 * 2;
    float* gh    = (float*)p; p += (size_t)4096 * 9 * 4;
    bf16* feat   = (bf16*)p; p += (size_t)4096 * 2304 * 2;
    float* partf = (float*)p; p += (size_t)12 * 4096 * 64 * 4;

    build_wicati<<<3072, 256, 0, stream>>>(Wi_f, Wi_i, Wi_o, Wi_c, WiCatI);
    build_whfio<<<2304, 256, 0, stream>>>(Wh_f, Wh_i, Wh_o, WhFIO);
    convert_f2b<<<(3 * 768 * 768 + 255) / 256, 256, 0, stream>>>(Wh_c, WhCb, 3 * 768 * 768);
    build_wg<<<48, 256, 0, stream>>>(Wi_g, Wgb);
    build_wgh<<<144, 256, 0, stream>>>(Wh_g, WgH);
    build_wlast<<<1152, 256, 0, stream>>>(W_last, Wlb);
    convert_f2b<<<4096, 256, 0, stream>>>(x, xb, 4096 * 256);
    init_state<<<12288, 256, 0, stream>>>(hidden0, current0, hb0, cb0);

    // hoisted layer-0 input-side work (x constant across t)
    gemm_bt<<<dim3(8, 32, 1), 256, 0, stream>>>(xb, 256, 0, WiCatI, 256, 0,
                                                ipre0i, 1024, 0, 256, 1, nullptr, 0);
    gin0_kernel<<<256, 256, 0, stream>>>(xb, Wi_g, gin0);

    for (int t = 0; t < 10; ++t) {
        bf16* hprev = (t & 1) ? hb1 : hb0;
        bf16* hnew  = (t & 1) ? hb0 : hb1;
        float* cprev = (t & 1) ? cb1 : cb0;
        float* cnew  = (t & 1) ? cb0 : cb1;

        // hg (z<3) + aux (z>=3) + gh, one launch
        gemm_hidden<<<dim3(6, 32, 6), 256, 0, stream>>>(
            hprev, WhFIO, WhCb, WgH, bi_g, bh_g, hgb, auxb, gh);

        gates_pre<<<256, 256, 0, stream>>>(
            ipre0i, gin0, gh,
            hgb, auxb, cprev,
            bi_f, bh_f, bi_i, bh_i, bi_o, bh_o, bi_c, bh_c,
            hnew, cnew);

        for (int l = 1; l < 3; ++l) {
            gemm_gates<<<dim3(8, 32), 256, 0, stream>>>(
                (const bf16*)(hnew + (l - 1) * 256), 768,
                WiCatI + (size_t)l * 1024 * 256,
                Wgb + (size_t)l * 16 * 256,
                hgb + (size_t)l * 4096 * 768,
                auxb + (size_t)l * 4096 * 768,
                gh + l * 3,
                cprev + (size_t)l * 4096 * 256,
                bi_f + l * 256, bh_f + l * 256,
                bi_i + l * 256, bh_i + l * 256,
                bi_o + l * 256, bh_o + l * 256,
                bi_c + l * 256, bh_c + l * 768,
                hnew + l * 256,
                cnew + (size_t)l * 4096 * 256,
                (l == 2 && t < 9) ? (feat + (size_t)t * 256) : (bf16*)nullptr);
        }
    }

    // final: K-split feat[4096,2304] @ Wlb[128,2304]^T into 12 partials of K=192
    gemm_bt<<<dim3(1, 32, 12), 256, 0, stream>>>(
        feat, 2304, 192, Wlb, 2304, 192,
        partf, 64, (long long)4096 * 64, 192, 3, nullptr, 64);
    final_reduce<<<704, 256, 0, stream>>>(partf, b_last, (float*)d_out);
}

// Round 8
// 1087.386 us; speedup vs baseline: 2.1365x; 1.2986x over previous
//
#include <hip/hip_runtime.h>
#include <hip/hip_bf16.h>

typedef __hip_bfloat16 bf16;
typedef __attribute__((ext_vector_type(8))) short frag8;   // 8 bf16 = 4 VGPRs
typedef __attribute__((ext_vector_type(4))) float f32x4;

#define BM 128
#define BN 128
#define BK 64
#define SK 72   // padded LDS stride for VGPR-staged kernels

__device__ __forceinline__ float sigm(float x) { return 1.f / (1.f + __expf(-x)); }

// async global->LDS, 16B/lane; lds base wave-uniform, lane scatters at +lane*16
__device__ __forceinline__ void lds_load16(const bf16* g, short* l) {
    __builtin_amdgcn_global_load_lds(
        (const __attribute__((address_space(1))) void*)g,
        (__attribute__((address_space(3))) void*)l, 16, 0, 0);
}

// C[m,n] = sum_k A[m,k] * W[n,k]; 128x128 tile, padded in-loop VGPR staging (no prefetch
// regs: r5/r6 spill lesson). Used for hoisted ipre0 GEMM and the K-split final GEMM.
// outmode: 0 fp32, 1 bf16, 2 sigmoid(acc+bias[n]) fp32 n<nbound, 3 raw fp32 n<nbound.
__global__ __launch_bounds__(256, 2)
void gemm_bt(const bf16* __restrict__ A, int lda, long long sAz,
             const bf16* __restrict__ W, int ldw, long long sWz,
             void* __restrict__ Cv, int ldc, long long sCz, int K,
             int outmode, const float* __restrict__ bias, int nbound)
{
    __shared__ short As[BM * SK];
    __shared__ short Bs[BN * SK];
    const int z = blockIdx.z;
    A += (size_t)z * sAz;
    W += (size_t)z * sWz;
    const int m0 = blockIdx.y * BM;
    const int n0 = blockIdx.x * BN;
    const int tid  = threadIdx.x;
    const int lane = tid & 63;
    const int wave = tid >> 6;
    const int wm = (wave >> 1) * 64;
    const int wn = (wave & 1) * 64;
    const int q   = lane >> 4;
    const int r16 = lane & 15;

    f32x4 acc[4][4] = {};

    const int trow = tid >> 3;         // 0..31
    const int tcol = (tid & 7) * 8;    // 16B chunk (bf16 elems)

    for (int k0 = 0; k0 < K; k0 += BK) {
        __syncthreads();
        #pragma unroll
        for (int p = 0; p < 4; ++p) {
            int rr = p * 32 + trow;
            *(uint4*)&As[rr * SK + tcol] =
                *(const uint4*)(A + (size_t)(m0 + rr) * lda + k0 + tcol);
            *(uint4*)&Bs[rr * SK + tcol] =
                *(const uint4*)(W + (size_t)(n0 + rr) * ldw + k0 + tcol);
        }
        __syncthreads();
        #pragma unroll
        for (int kk = 0; kk < 2; ++kk) {
            const int ko = kk * 32 + q * 8;
            frag8 af[4], bfr[4];
            #pragma unroll
            for (int i = 0; i < 4; ++i)
                af[i] = *(const frag8*)&As[(wm + i * 16 + r16) * SK + ko];
            #pragma unroll
            for (int j = 0; j < 4; ++j)
                bfr[j] = *(const frag8*)&Bs[(wn + j * 16 + r16) * SK + ko];
            #pragma unroll
            for (int i = 0; i < 4; ++i)
                #pragma unroll
                for (int j = 0; j < 4; ++j)
                    acc[i][j] = __builtin_amdgcn_mfma_f32_16x16x32_bf16(
                        af[i], bfr[j], acc[i][j], 0, 0, 0);
        }
    }

    if (outmode == 0) {
        float* C = (float*)Cv + (size_t)z * sCz;
        #pragma unroll
        for (int i = 0; i < 4; ++i)
            #pragma unroll
            for (int rr = 0; rr < 4; ++rr) {
                int row = m0 + wm + i * 16 + q * 4 + rr;
                float* crow = C + (size_t)row * ldc + n0 + wn + r16;
                #pragma unroll
                for (int j = 0; j < 4; ++j) crow[j * 16] = acc[i][j][rr];
            }
    } else if (outmode == 1) {
        bf16* C = (bf16*)Cv + (size_t)z * sCz;
        #pragma unroll
        for (int i = 0; i < 4; ++i)
            #pragma unroll
            for (int rr = 0; rr < 4; ++rr) {
                int row = m0 + wm + i * 16 + q * 4 + rr;
                bf16* crow = C + (size_t)row * ldc + n0 + wn + r16;
                #pragma unroll
                for (int j = 0; j < 4; ++j) crow[j * 16] = __float2bfloat16(acc[i][j][rr]);
            }
    } else if (outmode == 2) {
        float* C = (float*)Cv + (size_t)z * sCz;
        #pragma unroll
        for (int i = 0; i < 4; ++i)
            #pragma unroll
            for (int rr = 0; rr < 4; ++rr) {
                int row = m0 + wm + i * 16 + q * 4 + rr;
                #pragma unroll
                for (int j = 0; j < 4; ++j) {
                    int col = n0 + wn + j * 16 + r16;
                    if (col < nbound)
                        C[(size_t)row * ldc + col] = sigm(acc[i][j][rr] + bias[col]);
                }
            }
    } else {
        float* C = (float*)Cv + (size_t)z * sCz;
        #pragma unroll
        for (int i = 0; i < 4; ++i)
            #pragma unroll
            for (int rr = 0; rr < 4; ++rr) {
                int row = m0 + wm + i * 16 + q * 4 + rr;
                #pragma unroll
                for (int j = 0; j < 4; ++j) {
                    int col = n0 + wn + j * 16 + r16;
                    if (col < nbound)
                        C[(size_t)row * ldc + col] = acc[i][j][rr];
                }
            }
    }
}

// ---------------- merged hidden-side kernel (m97-style global_load_lds staging) ----------------
// Grid (6, 32, 6), 1152 blocks = 4.5/CU (healthy occupancy for the async-staging regime;
// r4's regression was this technique at 1 block/CU). LDS unpadded (lane-sequential scatter).
__global__ __launch_bounds__(256, 2)
void gemm_hidden(const bf16* __restrict__ hprev,
                 const bf16* __restrict__ WhFIO,  // [3][768][256]
                 const bf16* __restrict__ WhCb,   // [3][768][768]
                 const bf16* __restrict__ WgH,    // [3][16][768], rows 0..2 = Wh_g[l]
                 const float* __restrict__ big, const float* __restrict__ bhg,  // [9]
                 bf16* __restrict__ hgb,          // [3][4096][768]
                 bf16* __restrict__ auxb,         // [3][4096][768]
                 float* __restrict__ gh)          // [4096][9]
{
    __shared__ __align__(16) short As[BM * 64];
    __shared__ __align__(16) short Bs[BN * 64];
    __shared__ __align__(16) short Bg[16 * 64];

    const int z = blockIdx.z;
    const bool isaux = z >= 3;
    const int l = isaux ? z - 3 : z;
    const bf16* A = hprev + (isaux ? 0 : l * 256);
    const int K = isaux ? 768 : 256;
    const bf16* W = isaux ? (WhCb + (size_t)l * 768 * 768) : (WhFIO + (size_t)l * 768 * 256);
    const int ldw = isaux ? 768 : 256;
    bf16* C = (isaux ? auxb : hgb) + (size_t)l * 4096 * 768;
    const bool do_g = isaux && (blockIdx.x == 0);

    const int m0 = blockIdx.y * BM;
    const int n0 = blockIdx.x * BN;
    const int tid  = threadIdx.x;
    const int lane = tid & 63;
    const int wave = tid >> 6;
    const int wm = (wave >> 1) * 64;
    const int wn = (wave & 1) * 64;
    const int q   = lane >> 4;
    const int r16 = lane & 15;

    f32x4 acc[4][4] = {};
    f32x4 accg[4] = {};

    const int srow = lane >> 3;          // 0..7 row within 8-row chunk
    const int scol = (lane & 7) * 8;     // 16B chunk offset (elems)
    const bf16* WgL = WgH + (size_t)l * 16 * 768;

    for (int k0 = 0; k0 < K; k0 += BK) {
        __syncthreads();
        #pragma unroll
        for (int p = 0; p < 4; ++p) {
            int rbase = (wave * 4 + p) * 8;
            lds_load16(A + (size_t)(m0 + rbase + srow) * 768 + k0 + scol, &As[rbase * 64]);
            lds_load16(W + (size_t)(n0 + rbase + srow) * ldw + k0 + scol, &Bs[rbase * 64]);
        }
        if (do_g && wave < 2)
            lds_load16(WgL + (size_t)(wave * 8 + srow) * 768 + k0 + scol, &Bg[wave * 8 * 64]);
        __syncthreads();
        #pragma unroll
        for (int kk = 0; kk < 2; ++kk) {
            const int ko = kk * 32 + q * 8;
            frag8 af[4], bfr[4];
            #pragma unroll
            for (int i = 0; i < 4; ++i)
                af[i] = *(const frag8*)&As[(wm + i * 16 + r16) * 64 + ko];
            #pragma unroll
            for (int j = 0; j < 4; ++j)
                bfr[j] = *(const frag8*)&Bs[(wn + j * 16 + r16) * 64 + ko];
            #pragma unroll
            for (int i = 0; i < 4; ++i)
                #pragma unroll
                for (int j = 0; j < 4; ++j)
                    acc[i][j] = __builtin_amdgcn_mfma_f32_16x16x32_bf16(
                        af[i], bfr[j], acc[i][j], 0, 0, 0);
            if (do_g) {
                frag8 bg = *(const frag8*)&Bg[r16 * 64 + ko];
                #pragma unroll
                for (int i = 0; i < 4; ++i)
                    accg[i] = __builtin_amdgcn_mfma_f32_16x16x32_bf16(
                        af[i], bg, accg[i], 0, 0, 0);
            }
        }
    }

    #pragma unroll
    for (int i = 0; i < 4; ++i)
        #pragma unroll
        for (int rr = 0; rr < 4; ++rr) {
            int row = m0 + wm + i * 16 + q * 4 + rr;
            bf16* crow = C + (size_t)row * 768 + n0 + wn + r16;
            #pragma unroll
            for (int j = 0; j < 4; ++j) crow[j * 16] = __float2bfloat16(acc[i][j][rr]);
        }
    if (do_g && wn == 0 && r16 < 3) {
        float bsum = big[l * 3 + r16] + bhg[l * 3 + r16];
        #pragma unroll
        for (int i = 0; i < 4; ++i)
            #pragma unroll
            for (int rr = 0; rr < 4; ++rr) {
                int row = m0 + wm + i * 16 + q * 4 + rr;
                gh[(size_t)row * 9 + l * 3 + r16] = accg[i][rr] + bsum;
            }
    }
}

// ---------------- fused input-GEMM + gates (layers 1,2) ----------------
// 64m x 128n tile, grid (8, 64) = 512 blocks = 2/CU. Padded in-loop staging.
#define GM 64
struct Stage { short As[GM * SK]; short Bs[BN * SK]; short Bg[16 * SK]; };
union SMemU { Stage s; float ct[GM * 128]; };

__global__ __launch_bounds__(256, 2)
void gemm_gates(const bf16* __restrict__ A, int lda,
                const bf16* __restrict__ Wi, const bf16* __restrict__ Wg,
                const bf16* __restrict__ hg_l,   // [4096][768] bf16
                const bf16* __restrict__ aux_l,  // [4096][768] bf16
                const float* __restrict__ ghc_l, // gh + l*3, stride 9, biases folded
                const float* __restrict__ cprev,
                const float* __restrict__ bif, const float* __restrict__ bhf,
                const float* __restrict__ bii, const float* __restrict__ bhi,
                const float* __restrict__ bio, const float* __restrict__ bho,
                const float* __restrict__ bic, const float* __restrict__ bhc, // [768]
                bf16*  __restrict__ hnew,   // col-slice base, row stride 768
                float* __restrict__ cnew,
                bf16*  __restrict__ featc)  // nullable, row stride 2304
{
    __shared__ SMemU sm;
    __shared__ float gsh[GM * 3];

    const int m0 = blockIdx.y * GM;
    const int n0 = blockIdx.x * BN;
    const int jbase = n0 >> 2;
    const int tid  = threadIdx.x;
    const int lane = tid & 63;
    const int wave = tid >> 6;
    const int wm = (wave >> 1) * 32;   // 2x2 waves, each 32m x 64n
    const int wn = (wave & 1) * 64;
    const int q   = lane >> 4;
    const int r16 = lane & 15;

    f32x4 acc[2][4] = {};
    f32x4 accg[2] = {};

    const int trow = tid >> 3;
    const int tcol = (tid & 7) * 8;

    for (int k0 = 0; k0 < 256; k0 += BK) {
        __syncthreads();
        {
            // A: 64 rows (2 chunks), B: 128 rows (4 chunks)
            if (trow < 32) {
                #pragma unroll
                for (int p = 0; p < 2; ++p) {
                    int rr = p * 32 + trow;
                    *(uint4*)&sm.s.As[rr * SK + tcol] =
                        *(const uint4*)(A + (size_t)(m0 + rr) * lda + k0 + tcol);
                }
            }
            #pragma unroll
            for (int p = 0; p < 4; ++p) {
                int rr = p * 32 + trow;
                *(uint4*)&sm.s.Bs[rr * SK + tcol] =
                    *(const uint4*)(Wi + (size_t)(n0 + rr) * 256 + k0 + tcol);
            }
            if (tid < 128)
                *(uint4*)&sm.s.Bg[(tid >> 3) * SK + tcol] =
                    *(const uint4*)(Wg + (size_t)(tid >> 3) * 256 + k0 + tcol);
        }
        __syncthreads();
        #pragma unroll
        for (int kk = 0; kk < 2; ++kk) {
            const int ko = kk * 32 + q * 8;
            frag8 af[2], bfr[4], bg;
            bg = *(const frag8*)&sm.s.Bg[r16 * SK + ko];
            #pragma unroll
            for (int i = 0; i < 2; ++i)
                af[i] = *(const frag8*)&sm.s.As[(wm + i * 16 + r16) * SK + ko];
            #pragma unroll
            for (int j = 0; j < 4; ++j)
                bfr[j] = *(const frag8*)&sm.s.Bs[(wn + j * 16 + r16) * SK + ko];
            #pragma unroll
            for (int i = 0; i < 2; ++i) {
                #pragma unroll
                for (int j = 0; j < 4; ++j)
                    acc[i][j] = __builtin_amdgcn_mfma_f32_16x16x32_bf16(
                        af[i], bfr[j], acc[i][j], 0, 0, 0);
                accg[i] = __builtin_amdgcn_mfma_f32_16x16x32_bf16(
                    af[i], bg, accg[i], 0, 0, 0);
            }
        }
    }

    __syncthreads();   // staging reads done; sm union becomes ct
    // g values: waves with wn==0 (0 and 2) cover rows 0..63
    if (wn == 0 && r16 < 3) {
        #pragma unroll
        for (int i = 0; i < 2; ++i)
            #pragma unroll
            for (int rr = 0; rr < 4; ++rr) {
                int row = wm + i * 16 + q * 4 + rr;
                gsh[row * 3 + r16] = sigm(accg[i][rr] + ghc_l[(size_t)(m0 + row) * 9 + r16]);
            }
    }
    // dump C tile (rotate-swizzled float4 groups)
    #pragma unroll
    for (int i = 0; i < 2; ++i)
        #pragma unroll
        for (int rr = 0; rr < 4; ++rr) {
            int rowl = wm + i * 16 + q * 4 + rr;
            #pragma unroll
            for (int jr = 0; jr < 4; ++jr) {
                int col = wn + jr * 16 + r16;
                sm.ct[rowl * 128 + ((col + 4 * rowl) & 127)] = acc[i][jr][rr];
            }
        }
    __syncthreads();

    const int jj = tid & 31;
    const int r0 = (tid >> 5) * 8;
    const int j  = jbase + jj;
    const float vbif = bif[j], vbhf = bhf[j];
    const float vbii = bii[j], vbhi = bhi[j];
    const float vbio = bio[j], vbho = bho[j];
    const float vbic = bic[j];
    const float vbc0 = bhc[j], vbc1 = bhc[256 + j], vbc2 = bhc[512 + j];

    for (int ri = 0; ri < 8; ++ri) {
        int rowl = r0 + ri;
        size_t b = m0 + rowl;
        float4 pre = *(float4*)&sm.ct[rowl * 128 + ((4 * jj + 4 * rowl) & 127)];
        float g0 = gsh[rowl * 3 + 0];
        float g1 = gsh[rowl * 3 + 1];
        float g2 = gsh[rowl * 3 + 2];
        float hgf = __bfloat162float(hg_l[b * 768 + j]);
        float hgi = __bfloat162float(hg_l[b * 768 + 256 + j]);
        float hgo = __bfloat162float(hg_l[b * 768 + 512 + j]);
        float ax0 = __bfloat162float(aux_l[b * 768 + j]);
        float ax1 = __bfloat162float(aux_l[b * 768 + 256 + j]);
        float ax2 = __bfloat162float(aux_l[b * 768 + 512 + j]);
        float f  = sigm(pre.x + vbif + hgf + vbhf);
        float ii = sigm(pre.y + vbii + hgi + vbhi);
        float o  = sigm(pre.z + vbio + hgo + vbho);
        float av = g0 * (ax0 + vbc0) + g1 * (ax1 + vbc1) + g2 * (ax2 + vbc2);
        float ct = tanhf(pre.w + vbic + av);
        float c  = f * cprev[b * 256 + j] + ii * ct;
        float h  = o * c;
        cnew[b * 256 + j] = c;
        hnew[b * 768 + j] = __float2bfloat16(h);
        if (featc) featc[b * 2304 + j] = __float2bfloat16(h);
    }
}

// ---------------- layer-0 gates from precomputed pre-acts ----------------
__global__ __launch_bounds__(256)
void gates_pre(const bf16* __restrict__ ipre0i, const float* __restrict__ gin0,
               const float* __restrict__ ghc,
               const bf16* __restrict__ hg_l, const bf16* __restrict__ aux_l,
               const float* __restrict__ cprev,
               const float* __restrict__ bif, const float* __restrict__ bhf,
               const float* __restrict__ bii, const float* __restrict__ bhi,
               const float* __restrict__ bio, const float* __restrict__ bho,
               const float* __restrict__ bic, const float* __restrict__ bhc,
               bf16* __restrict__ hnew, float* __restrict__ cnew)
{
    const int j = threadIdx.x;
    const int b0 = blockIdx.x * 16;
    const float vbif = bif[j], vbhf = bhf[j];
    const float vbii = bii[j], vbhi = bhi[j];
    const float vbio = bio[j], vbho = bho[j];
    const float vbic = bic[j];
    const float vbc0 = bhc[j], vbc1 = bhc[256 + j], vbc2 = bhc[512 + j];

    for (int r = 0; r < 16; ++r) {
        const size_t b = b0 + r;
        const bf16* ip4 = ipre0i + b * 1024 + 4 * j;
        float pf = __bfloat162float(ip4[0]);
        float pi = __bfloat162float(ip4[1]);
        float po = __bfloat162float(ip4[2]);
        float pc = __bfloat162float(ip4[3]);
        float g0 = sigm(gin0[b * 3 + 0] + ghc[b * 9 + 0]);
        float g1 = sigm(gin0[b * 3 + 1] + ghc[b * 9 + 1]);
        float g2 = sigm(gin0[b * 3 + 2] + ghc[b * 9 + 2]);
        float hgf = __bfloat162float(hg_l[b * 768 + j]);
        float hgi = __bfloat162float(hg_l[b * 768 + 256 + j]);
        float hgo = __bfloat162float(hg_l[b * 768 + 512 + j]);
        float ax0 = __bfloat162float(aux_l[b * 768 + j]);
        float ax1 = __bfloat162float(aux_l[b * 768 + 256 + j]);
        float ax2 = __bfloat162float(aux_l[b * 768 + 512 + j]);
        float f  = sigm(pf + vbif + hgf + vbhf);
        float ii = sigm(pi + vbii + hgi + vbhi);
        float o  = sigm(po + vbio + hgo + vbho);
        float av = g0 * (ax0 + vbc0) + g1 * (ax1 + vbc1) + g2 * (ax2 + vbc2);
        float ct = tanhf(pc + vbic + av);
        float c  = f * cprev[b * 256 + j] + ii * ct;
        float h  = o * c;
        cnew[b * 256 + j] = c;
        hnew[b * 768 + j] = __float2bfloat16(h);
    }
}

// gin0[b][s] = xb[b,:] . Wi_g[0][s][:]  (no bias; constant over t)
__global__ __launch_bounds__(256)
void gin0_kernel(const bf16* __restrict__ xb, const float* __restrict__ Wig,
                 float* __restrict__ gout)
{
    const int wave = threadIdx.x >> 6, lane = threadIdx.x & 63;
    for (int rep = 0; rep < 4; ++rep) {
        size_t b = (size_t)blockIdx.x * 16 + wave * 4 + rep;
        float hv[4];
        #pragma unroll
        for (int m = 0; m < 4; ++m)
            hv[m] = __bfloat162float(xb[b * 256 + m * 64 + lane]);
        float p[3];
        #pragma unroll
        for (int s = 0; s < 3; ++s) {
            float t = 0.f;
            const float* w = Wig + (size_t)s * 256;
            #pragma unroll
            for (int m = 0; m < 4; ++m) t += hv[m] * w[m * 64 + lane];
            p[s] = t;
        }
        #pragma unroll
        for (int off = 32; off; off >>= 1)
            #pragma unroll
            for (int s = 0; s < 3; ++s) p[s] += __shfl_down(p[s], off);
        if (lane == 0) {
            #pragma unroll
            for (int s = 0; s < 3; ++s) gout[b * 3 + s] = p[s];
        }
    }
}

// out[b][n] = sigm(bias[n] + sum_z part[z][b][n]), n<44
__global__ __launch_bounds__(256)
void final_reduce(const float* __restrict__ part, const float* __restrict__ bl,
                  float* __restrict__ out)
{
    int idx = blockIdx.x * 256 + threadIdx.x;
    if (idx >= 4096 * 44) return;
    int b = idx / 44, n = idx - b * 44;
    float s = bl[n];
    #pragma unroll
    for (int z = 0; z < 12; ++z) s += part[(size_t)z * 4096 * 64 + (size_t)b * 64 + n];
    out[idx] = sigm(s);
}

// ---------------- prep kernels ----------------
__global__ void build_wicati(const float* __restrict__ Wf, const float* __restrict__ Wi,
                             const float* __restrict__ Wo, const float* __restrict__ Wc,
                             bf16* __restrict__ out)
{
    int idx = blockIdx.x * 256 + threadIdx.x;  // 3*1024*256
    int k = idx & 255, n = (idx >> 8) & 1023, l = idx >> 18;
    int j = n >> 2, g = n & 3;
    const float* src = (g == 0) ? Wf : (g == 1) ? Wi : (g == 2) ? Wo : Wc;
    out[idx] = __float2bfloat16(src[l * 65536 + j * 256 + k]);
}

__global__ void build_whfio(const float* __restrict__ Wf, const float* __restrict__ Wi,
                            const float* __restrict__ Wo, bf16* __restrict__ out)
{
    int idx = blockIdx.x * 256 + threadIdx.x;  // 3*768*256
    int k = idx & 255, n = (idx >> 8) % 768, l = idx / 196608;
    const float* src = (n < 256) ? Wf : (n < 512) ? Wi : Wo;
    out[idx] = __float2bfloat16(src[l * 65536 + (n & 255) * 256 + k]);
}

__global__ void build_wg(const float* __restrict__ Wig, bf16* __restrict__ out)
{
    int idx = blockIdx.x * 256 + threadIdx.x;  // 3*16*256
    int k = idx & 255, r = (idx >> 8) & 15, l = idx >> 12;
    out[idx] = (r < 3) ? __float2bfloat16(Wig[l * 768 + r * 256 + k]) : __float2bfloat16(0.f);
}

// WgH [3][16][768]: rows 0..2 = Wh_g[l], rest zero
__global__ void build_wgh(const float* __restrict__ Whg, bf16* __restrict__ out)
{
    int idx = blockIdx.x * 256 + threadIdx.x;  // 3*16*768
    int k = idx % 768, r = (idx / 768) & 15, l = idx / (16 * 768);
    out[idx] = (r < 3) ? __float2bfloat16(Whg[(l * 3 + r) * 768 + k]) : __float2bfloat16(0.f);
}

__global__ void build_wlast(const float* __restrict__ Wl, bf16* __restrict__ out)
{
    int idx = blockIdx.x * 256 + threadIdx.x;  // 128*2304
    int k = idx % 2304, n = idx / 2304;
    out[idx] = (n < 44) ? __float2bfloat16(Wl[n * 2304 + k]) : __float2bfloat16(0.f);
}

__global__ void convert_f2b(const float* __restrict__ in, bf16* __restrict__ out, int n)
{
    int idx = blockIdx.x * 256 + threadIdx.x;
    if (idx < n) out[idx] = __float2bfloat16(in[idx]);
}

__global__ void init_state(const float* __restrict__ hidden0, const float* __restrict__ current0,
                           bf16* __restrict__ hcat, float* __restrict__ c0)
{
    int idx = blockIdx.x * 256 + threadIdx.x;  // 3*4096*256
    int j = idx & 255, b = (idx >> 8) & 4095, l = idx >> 20;
    hcat[(size_t)b * 768 + l * 256 + j] = __float2bfloat16(hidden0[idx]);
    c0[idx] = current0[idx];
}

extern "C" void kernel_launch(void* const* d_in, const int* in_sizes, int n_in,
                              void* d_out, int out_size, void* d_ws, size_t ws_size,
                              hipStream_t stream)
{
    (void)in_sizes; (void)n_in; (void)out_size; (void)ws_size;
    const float* x        = (const float*)d_in[0];
    const float* hidden0  = (const float*)d_in[1];
    const float* current0 = (const float*)d_in[2];
    const float* Wi_f = (const float*)d_in[3];  const float* bi_f = (const float*)d_in[4];
    const float* Wi_i = (const float*)d_in[5];  const float* bi_i = (const float*)d_in[6];
    const float* Wi_o = (const float*)d_in[7];  const float* bi_o = (const float*)d_in[8];
    const float* Wi_c = (const float*)d_in[9];  const float* bi_c = (const float*)d_in[10];
    const float* Wi_g = (const float*)d_in[11]; const float* bi_g = (const float*)d_in[12];
    const float* Wh_f = (const float*)d_in[13]; const float* bh_f = (const float*)d_in[14];
    const float* Wh_i = (const float*)d_in[15]; const float* bh_i = (const float*)d_in[16];
    const float* Wh_o = (const float*)d_in[17]; const float* bh_o = (const float*)d_in[18];
    const float* Wh_g = (const float*)d_in[19]; const float* bh_g = (const float*)d_in[20];
    const float* Wh_c = (const float*)d_in[21]; const float* bh_c = (const float*)d_in[22];
    const float* W_last = (const float*)d_in[23]; const float* b_last = (const float*)d_in[24];

    char* p = (char*)d_ws;
    bf16* WiCatI = (bf16*)p; p += (size_t)3 * 1024 * 256 * 2;
    bf16* WhFIO  = (bf16*)p; p += (size_t)3 * 768 * 256 * 2;
    bf16* WhCb   = (bf16*)p; p += (size_t)3 * 768 * 768 * 2;
    bf16* Wgb    = (bf16*)p; p += (size_t)3 * 16 * 256 * 2;
    bf16* WgH    = (bf16*)p; p += (size_t)3 * 16 * 768 * 2;
    bf16* Wlb    = (bf16*)p; p += (size_t)128 * 2304 * 2;
    bf16* xb     = (bf16*)p; p += (size_t)4096 * 256 * 2;
    bf16* ipre0i = (bf16*)p; p += (size_t)4096 * 1024 * 2;
    float* gin0  = (float*)p; p += (size_t)4096 * 3 * 4;
    bf16* hb0    = (bf16*)p; p += (size_t)4096 * 768 * 2;
    bf16* hb1    = (bf16*)p; p += (size_t)4096 * 768 * 2;
    float* cb0   = (float*)p; p += (size_t)3 * 4096 * 256 * 4;
    float* cb1   = (float*)p; p += (size_t)3 * 4096 * 256 * 4;
    bf16* hgb    = (bf16*)p; p += (size_t)3 * 4096 * 768 * 2;
    bf16* auxb   = (bf16*)p; p += (size_t)3 * 4096 * 768 * 2;
    float* gh    = (float*)p; p += (size_t)4096 * 9 * 4;
    bf16* feat   = (bf16*)p; p += (size_t)4096 * 2304 * 2;
    float* partf = (float*)p; p += (size_t)12 * 4096 * 64 * 4;

    build_wicati<<<3072, 256, 0, stream>>>(Wi_f, Wi_i, Wi_o, Wi_c, WiCatI);
    build_whfio<<<2304, 256, 0, stream>>>(Wh_f, Wh_i, Wh_o, WhFIO);
    convert_f2b<<<(3 * 768 * 768 + 255) / 256, 256, 0, stream>>>(Wh_c, WhCb, 3 * 768 * 768);
    build_wg<<<48, 256, 0, stream>>>(Wi_g, Wgb);
    build_wgh<<<144, 256, 0, stream>>>(Wh_g, WgH);
    build_wlast<<<1152, 256, 0, stream>>>(W_last, Wlb);
    convert_f2b<<<4096, 256, 0, stream>>>(x, xb, 4096 * 256);
    init_state<<<12288, 256, 0, stream>>>(hidden0, current0, hb0, cb0);

    // hoisted layer-0 input-side work (x constant across t)
    gemm_bt<<<dim3(8, 32, 1), 256, 0, stream>>>(xb, 256, 0, WiCatI, 256, 0,
                                                ipre0i, 1024, 0, 256, 1, nullptr, 0);
    gin0_kernel<<<256, 256, 0, stream>>>(xb, Wi_g, gin0);

    for (int t = 0; t < 10; ++t) {
        bf16* hprev = (t & 1) ? hb1 : hb0;
        bf16* hnew  = (t & 1) ? hb0 : hb1;
        float* cprev = (t & 1) ? cb1 : cb0;
        float* cnew  = (t & 1) ? cb0 : cb1;

        gemm_hidden<<<dim3(6, 32, 6), 256, 0, stream>>>(
            hprev, WhFIO, WhCb, WgH, bi_g, bh_g, hgb, auxb, gh);

        gates_pre<<<256, 256, 0, stream>>>(
            ipre0i, gin0, gh,
            hgb, auxb, cprev,
            bi_f, bh_f, bi_i, bh_i, bi_o, bh_o, bi_c, bh_c,
            hnew, cnew);

        for (int l = 1; l < 3; ++l) {
            gemm_gates<<<dim3(8, 64), 256, 0, stream>>>(
                (const bf16*)(hnew + (l - 1) * 256), 768,
                WiCatI + (size_t)l * 1024 * 256,
                Wgb + (size_t)l * 16 * 256,
                hgb + (size_t)l * 4096 * 768,
                auxb + (size_t)l * 4096 * 768,
                gh + l * 3,
                cprev + (size_t)l * 4096 * 256,
                bi_f + l * 256, bh_f + l * 256,
                bi_i + l * 256, bh_i + l * 256,
                bi_o + l * 256, bh_o + l * 256,
                bi_c + l * 256, bh_c + l * 768,
                hnew + l * 256,
                cnew + (size_t)l * 4096 * 256,
                (l == 2 && t < 9) ? (feat + (size_t)t * 256) : (bf16*)nullptr);
        }
    }

    // final: K-split feat[4096,2304] @ Wlb[128,2304]^T into 12 partials of K=192
    gemm_bt<<<dim3(1, 32, 12), 256, 0, stream>>>(
        feat, 2304, 192, Wlb, 2304, 192,
        partf, 64, (long long)4096 * 64, 192, 3, nullptr, 64);
    final_reduce<<<704, 256, 0, stream>>>(partf, b_last, (float*)d_out);
}

// Round 9
// 929.529 us; speedup vs baseline: 2.4993x; 1.1698x over previous
//
#include <hip/hip_runtime.h>
#include <hip/hip_bf16.h>

typedef __hip_bfloat16 bf16;
typedef __attribute__((ext_vector_type(8))) short frag8;   // 8 bf16 = 4 VGPRs
typedef __attribute__((ext_vector_type(4))) float f32x4;

#define BM 128
#define BN 128
#define BK 64
#define SK 72   // padded LDS stride for VGPR-staged kernels

__device__ __forceinline__ float sigm(float x) { return 1.f / (1.f + __expf(-x)); }

// async global->LDS, 16B/lane; lds base wave-uniform, lane scatters at +lane*16
__device__ __forceinline__ void lds_load16(const bf16* g, short* l) {
    __builtin_amdgcn_global_load_lds(
        (const __attribute__((address_space(1))) void*)g,
        (__attribute__((address_space(3))) void*)l, 16, 0, 0);
}

// C[m,n] = sum_k A[m,k] * W[n,k]; 128x128 tile, padded in-loop VGPR staging (no prefetch
// regs: r5/r6 spill lesson). Used for hoisted ipre0 GEMM and the K-split final GEMM.
// outmode: 0 fp32, 1 bf16, 2 sigmoid(acc+bias[n]) fp32 n<nbound, 3 raw fp32 n<nbound.
__global__ __launch_bounds__(256, 2)
void gemm_bt(const bf16* __restrict__ A, int lda, long long sAz,
             const bf16* __restrict__ W, int ldw, long long sWz,
             void* __restrict__ Cv, int ldc, long long sCz, int K,
             int outmode, const float* __restrict__ bias, int nbound)
{
    __shared__ short As[BM * SK];
    __shared__ short Bs[BN * SK];
    const int z = blockIdx.z;
    A += (size_t)z * sAz;
    W += (size_t)z * sWz;
    const int m0 = blockIdx.y * BM;
    const int n0 = blockIdx.x * BN;
    const int tid  = threadIdx.x;
    const int lane = tid & 63;
    const int wave = tid >> 6;
    const int wm = (wave >> 1) * 64;
    const int wn = (wave & 1) * 64;
    const int q   = lane >> 4;
    const int r16 = lane & 15;

    f32x4 acc[4][4] = {};

    const int trow = tid >> 3;         // 0..31
    const int tcol = (tid & 7) * 8;    // 16B chunk (bf16 elems)

    for (int k0 = 0; k0 < K; k0 += BK) {
        __syncthreads();
        #pragma unroll
        for (int p = 0; p < 4; ++p) {
            int rr = p * 32 + trow;
            *(uint4*)&As[rr * SK + tcol] =
                *(const uint4*)(A + (size_t)(m0 + rr) * lda + k0 + tcol);
            *(uint4*)&Bs[rr * SK + tcol] =
                *(const uint4*)(W + (size_t)(n0 + rr) * ldw + k0 + tcol);
        }
        __syncthreads();
        #pragma unroll
        for (int kk = 0; kk < 2; ++kk) {
            const int ko = kk * 32 + q * 8;
            frag8 af[4], bfr[4];
            #pragma unroll
            for (int i = 0; i < 4; ++i)
                af[i] = *(const frag8*)&As[(wm + i * 16 + r16) * SK + ko];
            #pragma unroll
            for (int j = 0; j < 4; ++j)
                bfr[j] = *(const frag8*)&Bs[(wn + j * 16 + r16) * SK + ko];
            #pragma unroll
            for (int i = 0; i < 4; ++i)
                #pragma unroll
                for (int j = 0; j < 4; ++j)
                    acc[i][j] = __builtin_amdgcn_mfma_f32_16x16x32_bf16(
                        af[i], bfr[j], acc[i][j], 0, 0, 0);
        }
    }

    if (outmode == 0) {
        float* C = (float*)Cv + (size_t)z * sCz;
        #pragma unroll
        for (int i = 0; i < 4; ++i)
            #pragma unroll
            for (int rr = 0; rr < 4; ++rr) {
                int row = m0 + wm + i * 16 + q * 4 + rr;
                float* crow = C + (size_t)row * ldc + n0 + wn + r16;
                #pragma unroll
                for (int j = 0; j < 4; ++j) crow[j * 16] = acc[i][j][rr];
            }
    } else if (outmode == 1) {
        bf16* C = (bf16*)Cv + (size_t)z * sCz;
        #pragma unroll
        for (int i = 0; i < 4; ++i)
            #pragma unroll
            for (int rr = 0; rr < 4; ++rr) {
                int row = m0 + wm + i * 16 + q * 4 + rr;
                bf16* crow = C + (size_t)row * ldc + n0 + wn + r16;
                #pragma unroll
                for (int j = 0; j < 4; ++j) crow[j * 16] = __float2bfloat16(acc[i][j][rr]);
            }
    } else if (outmode == 2) {
        float* C = (float*)Cv + (size_t)z * sCz;
        #pragma unroll
        for (int i = 0; i < 4; ++i)
            #pragma unroll
            for (int rr = 0; rr < 4; ++rr) {
                int row = m0 + wm + i * 16 + q * 4 + rr;
                #pragma unroll
                for (int j = 0; j < 4; ++j) {
                    int col = n0 + wn + j * 16 + r16;
                    if (col < nbound)
                        C[(size_t)row * ldc + col] = sigm(acc[i][j][rr] + bias[col]);
                }
            }
    } else {
        float* C = (float*)Cv + (size_t)z * sCz;
        #pragma unroll
        for (int i = 0; i < 4; ++i)
            #pragma unroll
            for (int rr = 0; rr < 4; ++rr) {
                int row = m0 + wm + i * 16 + q * 4 + rr;
                #pragma unroll
                for (int j = 0; j < 4; ++j) {
                    int col = n0 + wn + j * 16 + r16;
                    if (col < nbound)
                        C[(size_t)row * ldc + col] = acc[i][j][rr];
                }
            }
    }
}

// ---------------- merged hidden-side kernel (m97-style global_load_lds staging) ----------------
// Grid (36, 32): zi = x%6 (heavy K=768 aux and light K=256 hg interleave in dispatch
// order -> no all-heavy tail), xt = x/6 is the N-tile. LDS unpadded (lane scatter).
__global__ __launch_bounds__(256, 2)
void gemm_hidden(const bf16* __restrict__ hprev,
                 const bf16* __restrict__ WhFIO,  // [3][768][256]
                 const bf16* __restrict__ WhCb,   // [3][768][768]
                 const bf16* __restrict__ WgH,    // [3][16][768], rows 0..2 = Wh_g[l]
                 const float* __restrict__ big, const float* __restrict__ bhg,  // [9]
                 bf16* __restrict__ hgb,          // [3][4096][768]
                 bf16* __restrict__ auxb,         // [3][4096][768]
                 float* __restrict__ gh)          // [4096][9]
{
    __shared__ __align__(16) short As[BM * 64];
    __shared__ __align__(16) short Bs[BN * 64];
    __shared__ __align__(16) short Bg[16 * 64];

    const int zi = blockIdx.x % 6;
    const int xt = blockIdx.x / 6;
    const bool isaux = zi >= 3;
    const int l = isaux ? zi - 3 : zi;
    const bf16* A = hprev + (isaux ? 0 : l * 256);
    const int K = isaux ? 768 : 256;
    const bf16* W = isaux ? (WhCb + (size_t)l * 768 * 768) : (WhFIO + (size_t)l * 768 * 256);
    const int ldw = isaux ? 768 : 256;
    bf16* C = (isaux ? auxb : hgb) + (size_t)l * 4096 * 768;
    const bool do_g = isaux && (xt == 0);

    const int m0 = blockIdx.y * BM;
    const int n0 = xt * BN;
    const int tid  = threadIdx.x;
    const int lane = tid & 63;
    const int wave = tid >> 6;
    const int wm = (wave >> 1) * 64;
    const int wn = (wave & 1) * 64;
    const int q   = lane >> 4;
    const int r16 = lane & 15;

    f32x4 acc[4][4] = {};
    f32x4 accg[4] = {};

    const int srow = lane >> 3;          // 0..7 row within 8-row chunk
    const int scol = (lane & 7) * 8;     // 16B chunk offset (elems)
    const bf16* WgL = WgH + (size_t)l * 16 * 768;

    for (int k0 = 0; k0 < K; k0 += BK) {
        __syncthreads();
        #pragma unroll
        for (int p = 0; p < 4; ++p) {
            int rbase = (wave * 4 + p) * 8;
            lds_load16(A + (size_t)(m0 + rbase + srow) * 768 + k0 + scol, &As[rbase * 64]);
            lds_load16(W + (size_t)(n0 + rbase + srow) * ldw + k0 + scol, &Bs[rbase * 64]);
        }
        if (do_g && wave < 2)
            lds_load16(WgL + (size_t)(wave * 8 + srow) * 768 + k0 + scol, &Bg[wave * 8 * 64]);
        __syncthreads();
        #pragma unroll
        for (int kk = 0; kk < 2; ++kk) {
            const int ko = kk * 32 + q * 8;
            frag8 af[4], bfr[4];
            #pragma unroll
            for (int i = 0; i < 4; ++i)
                af[i] = *(const frag8*)&As[(wm + i * 16 + r16) * 64 + ko];
            #pragma unroll
            for (int j = 0; j < 4; ++j)
                bfr[j] = *(const frag8*)&Bs[(wn + j * 16 + r16) * 64 + ko];
            #pragma unroll
            for (int i = 0; i < 4; ++i)
                #pragma unroll
                for (int j = 0; j < 4; ++j)
                    acc[i][j] = __builtin_amdgcn_mfma_f32_16x16x32_bf16(
                        af[i], bfr[j], acc[i][j], 0, 0, 0);
            if (do_g) {
                frag8 bg = *(const frag8*)&Bg[r16 * 64 + ko];
                #pragma unroll
                for (int i = 0; i < 4; ++i)
                    accg[i] = __builtin_amdgcn_mfma_f32_16x16x32_bf16(
                        af[i], bg, accg[i], 0, 0, 0);
            }
        }
    }

    #pragma unroll
    for (int i = 0; i < 4; ++i)
        #pragma unroll
        for (int rr = 0; rr < 4; ++rr) {
            int row = m0 + wm + i * 16 + q * 4 + rr;
            bf16* crow = C + (size_t)row * 768 + n0 + wn + r16;
            #pragma unroll
            for (int j = 0; j < 4; ++j) crow[j * 16] = __float2bfloat16(acc[i][j][rr]);
        }
    if (do_g && wn == 0 && r16 < 3) {
        float bsum = big[l * 3 + r16] + bhg[l * 3 + r16];
        #pragma unroll
        for (int i = 0; i < 4; ++i)
            #pragma unroll
            for (int rr = 0; rr < 4; ++rr) {
                int row = m0 + wm + i * 16 + q * 4 + rr;
                gh[(size_t)row * 9 + l * 3 + r16] = accg[i][rr] + bsum;
            }
    }
}

// ---------------- fused input-GEMM + gates (layers 1,2) ----------------
// 64m x 128n tile, grid (8, 64) = 512 blocks = 2/CU. m97-style async staging (unpadded).
#define GM 64
struct Stage { short As[GM * 64]; short Bs[BN * 64]; short Bg[16 * 64]; };
union SMemU { Stage s; float ct[GM * 128]; };

__global__ __launch_bounds__(256, 2)
void gemm_gates(const bf16* __restrict__ A, int lda,
                const bf16* __restrict__ Wi, const bf16* __restrict__ Wg,
                const bf16* __restrict__ hg_l,   // [4096][768] bf16
                const bf16* __restrict__ aux_l,  // [4096][768] bf16
                const float* __restrict__ ghc_l, // gh + l*3, stride 9, biases folded
                const float* __restrict__ cprev,
                const float* __restrict__ bif, const float* __restrict__ bhf,
                const float* __restrict__ bii, const float* __restrict__ bhi,
                const float* __restrict__ bio, const float* __restrict__ bho,
                const float* __restrict__ bic, const float* __restrict__ bhc, // [768]
                bf16*  __restrict__ hnew,   // col-slice base, row stride 768
                float* __restrict__ cnew,
                bf16*  __restrict__ featc)  // nullable, row stride 2304
{
    __shared__ __align__(16) SMemU sm;
    __shared__ float gsh[GM * 3];

    const int m0 = blockIdx.y * GM;
    const int n0 = blockIdx.x * BN;
    const int jbase = n0 >> 2;
    const int tid  = threadIdx.x;
    const int lane = tid & 63;
    const int wave = tid >> 6;
    const int wm = (wave >> 1) * 32;   // 2x2 waves, each 32m x 64n
    const int wn = (wave & 1) * 64;
    const int q   = lane >> 4;
    const int r16 = lane & 15;

    f32x4 acc[2][4] = {};
    f32x4 accg[2] = {};

    const int srow = lane >> 3;
    const int scol = (lane & 7) * 8;

    for (int k0 = 0; k0 < 256; k0 += BK) {
        __syncthreads();
        #pragma unroll
        for (int p = 0; p < 2; ++p) {
            int rbase = (wave * 2 + p) * 8;   // A: 64 rows = 8 chunks
            lds_load16(A + (size_t)(m0 + rbase + srow) * lda + k0 + scol, &sm.s.As[rbase * 64]);
        }
        #pragma unroll
        for (int p = 0; p < 4; ++p) {
            int rbase = (wave * 4 + p) * 8;   // B: 128 rows = 16 chunks
            lds_load16(Wi + (size_t)(n0 + rbase + srow) * 256 + k0 + scol, &sm.s.Bs[rbase * 64]);
        }
        if (wave < 2)
            lds_load16(Wg + (size_t)(wave * 8 + srow) * 256 + k0 + scol, &sm.s.Bg[wave * 8 * 64]);
        __syncthreads();
        #pragma unroll
        for (int kk = 0; kk < 2; ++kk) {
            const int ko = kk * 32 + q * 8;
            frag8 af[2], bfr[4], bg;
            bg = *(const frag8*)&sm.s.Bg[r16 * 64 + ko];
            #pragma unroll
            for (int i = 0; i < 2; ++i)
                af[i] = *(const frag8*)&sm.s.As[(wm + i * 16 + r16) * 64 + ko];
            #pragma unroll
            for (int j = 0; j < 4; ++j)
                bfr[j] = *(const frag8*)&sm.s.Bs[(wn + j * 16 + r16) * 64 + ko];
            #pragma unroll
            for (int i = 0; i < 2; ++i) {
                #pragma unroll
                for (int j = 0; j < 4; ++j)
                    acc[i][j] = __builtin_amdgcn_mfma_f32_16x16x32_bf16(
                        af[i], bfr[j], acc[i][j], 0, 0, 0);
                accg[i] = __builtin_amdgcn_mfma_f32_16x16x32_bf16(
                    af[i], bg, accg[i], 0, 0, 0);
            }
        }
    }

    __syncthreads();   // staging reads done; sm union becomes ct
    // g values: waves with wn==0 (0 and 2) cover rows 0..63
    if (wn == 0 && r16 < 3) {
        #pragma unroll
        for (int i = 0; i < 2; ++i)
            #pragma unroll
            for (int rr = 0; rr < 4; ++rr) {
                int row = wm + i * 16 + q * 4 + rr;
                gsh[row * 3 + r16] = sigm(accg[i][rr] + ghc_l[(size_t)(m0 + row) * 9 + r16]);
            }
    }
    // dump C tile (rotate-swizzled float4 groups)
    #pragma unroll
    for (int i = 0; i < 2; ++i)
        #pragma unroll
        for (int rr = 0; rr < 4; ++rr) {
            int rowl = wm + i * 16 + q * 4 + rr;
            #pragma unroll
            for (int jr = 0; jr < 4; ++jr) {
                int col = wn + jr * 16 + r16;
                sm.ct[rowl * 128 + ((col + 4 * rowl) & 127)] = acc[i][jr][rr];
            }
        }
    __syncthreads();

    const int jj = tid & 31;
    const int r0 = (tid >> 5) * 8;
    const int j  = jbase + jj;
    const float vbif = bif[j], vbhf = bhf[j];
    const float vbii = bii[j], vbhi = bhi[j];
    const float vbio = bio[j], vbho = bho[j];
    const float vbic = bic[j];
    const float vbc0 = bhc[j], vbc1 = bhc[256 + j], vbc2 = bhc[512 + j];

    for (int ri = 0; ri < 8; ++ri) {
        int rowl = r0 + ri;
        size_t b = m0 + rowl;
        float4 pre = *(float4*)&sm.ct[rowl * 128 + ((4 * jj + 4 * rowl) & 127)];
        float g0 = gsh[rowl * 3 + 0];
        float g1 = gsh[rowl * 3 + 1];
        float g2 = gsh[rowl * 3 + 2];
        float hgf = __bfloat162float(hg_l[b * 768 + j]);
        float hgi = __bfloat162float(hg_l[b * 768 + 256 + j]);
        float hgo = __bfloat162float(hg_l[b * 768 + 512 + j]);
        float ax0 = __bfloat162float(aux_l[b * 768 + j]);
        float ax1 = __bfloat162float(aux_l[b * 768 + 256 + j]);
        float ax2 = __bfloat162float(aux_l[b * 768 + 512 + j]);
        float f  = sigm(pre.x + vbif + hgf + vbhf);
        float ii = sigm(pre.y + vbii + hgi + vbhi);
        float o  = sigm(pre.z + vbio + hgo + vbho);
        float av = g0 * (ax0 + vbc0) + g1 * (ax1 + vbc1) + g2 * (ax2 + vbc2);
        float ct = tanhf(pre.w + vbic + av);
        float c  = f * cprev[b * 256 + j] + ii * ct;
        float h  = o * c;
        cnew[b * 256 + j] = c;
        hnew[b * 768 + j] = __float2bfloat16(h);
        if (featc) featc[b * 2304 + j] = __float2bfloat16(h);
    }
}

// ---------------- layer-0 gates from precomputed pre-acts ----------------
// 1024 blocks x 4 rows (was 256 x 16 — 1 block/CU serial-latency bound)
__global__ __launch_bounds__(256)
void gates_pre(const bf16* __restrict__ ipre0i, const float* __restrict__ gin0,
               const float* __restrict__ ghc,
               const bf16* __restrict__ hg_l, const bf16* __restrict__ aux_l,
               const float* __restrict__ cprev,
               const float* __restrict__ bif, const float* __restrict__ bhf,
               const float* __restrict__ bii, const float* __restrict__ bhi,
               const float* __restrict__ bio, const float* __restrict__ bho,
               const float* __restrict__ bic, const float* __restrict__ bhc,
               bf16* __restrict__ hnew, float* __restrict__ cnew)
{
    const int j = threadIdx.x;
    const int b0 = blockIdx.x * 4;
    const float vbif = bif[j], vbhf = bhf[j];
    const float vbii = bii[j], vbhi = bhi[j];
    const float vbio = bio[j], vbho = bho[j];
    const float vbic = bic[j];
    const float vbc0 = bhc[j], vbc1 = bhc[256 + j], vbc2 = bhc[512 + j];

    #pragma unroll
    for (int r = 0; r < 4; ++r) {
        const size_t b = b0 + r;
        const bf16* ip4 = ipre0i + b * 1024 + 4 * j;
        float pf = __bfloat162float(ip4[0]);
        float pi = __bfloat162float(ip4[1]);
        float po = __bfloat162float(ip4[2]);
        float pc = __bfloat162float(ip4[3]);
        float g0 = sigm(gin0[b * 3 + 0] + ghc[b * 9 + 0]);
        float g1 = sigm(gin0[b * 3 + 1] + ghc[b * 9 + 1]);
        float g2 = sigm(gin0[b * 3 + 2] + ghc[b * 9 + 2]);
        float hgf = __bfloat162float(hg_l[b * 768 + j]);
        float hgi = __bfloat162float(hg_l[b * 768 + 256 + j]);
        float hgo = __bfloat162float(hg_l[b * 768 + 512 + j]);
        float ax0 = __bfloat162float(aux_l[b * 768 + j]);
        float ax1 = __bfloat162float(aux_l[b * 768 + 256 + j]);
        float ax2 = __bfloat162float(aux_l[b * 768 + 512 + j]);
        float f  = sigm(pf + vbif + hgf + vbhf);
        float ii = sigm(pi + vbii + hgi + vbhi);
        float o  = sigm(po + vbio + hgo + vbho);
        float av = g0 * (ax0 + vbc0) + g1 * (ax1 + vbc1) + g2 * (ax2 + vbc2);
        float ct = tanhf(pc + vbic + av);
        float c  = f * cprev[b * 256 + j] + ii * ct;
        float h  = o * c;
        cnew[b * 256 + j] = c;
        hnew[b * 768 + j] = __float2bfloat16(h);
    }
}

// gin0[b][s] = xb[b,:] . Wi_g[0][s][:]  (no bias; constant over t)
__global__ __launch_bounds__(256)
void gin0_kernel(const bf16* __restrict__ xb, const float* __restrict__ Wig,
                 float* __restrict__ gout)
{
    const int wave = threadIdx.x >> 6, lane = threadIdx.x & 63;
    for (int rep = 0; rep < 4; ++rep) {
        size_t b = (size_t)blockIdx.x * 16 + wave * 4 + rep;
        float hv[4];
        #pragma unroll
        for (int m = 0; m < 4; ++m)
            hv[m] = __bfloat162float(xb[b * 256 + m * 64 + lane]);
        float p[3];
        #pragma unroll
        for (int s = 0; s < 3; ++s) {
            float t = 0.f;
            const float* w = Wig + (size_t)s * 256;
            #pragma unroll
            for (int m = 0; m < 4; ++m) t += hv[m] * w[m * 64 + lane];
            p[s] = t;
        }
        #pragma unroll
        for (int off = 32; off; off >>= 1)
            #pragma unroll
            for (int s = 0; s < 3; ++s) p[s] += __shfl_down(p[s], off);
        if (lane == 0) {
            #pragma unroll
            for (int s = 0; s < 3; ++s) gout[b * 3 + s] = p[s];
        }
    }
}

// out[b][n] = sigm(bias[n] + sum_z part[z][b][n]), n<44
__global__ __launch_bounds__(256)
void final_reduce(const float* __restrict__ part, const float* __restrict__ bl,
                  float* __restrict__ out)
{
    int idx = blockIdx.x * 256 + threadIdx.x;
    if (idx >= 4096 * 44) return;
    int b = idx / 44, n = idx - b * 44;
    float s = bl[n];
    #pragma unroll
    for (int z = 0; z < 12; ++z) s += part[(size_t)z * 4096 * 64 + (size_t)b * 64 + n];
    out[idx] = sigm(s);
}

// ---------------- prep kernels ----------------
__global__ void build_wicati(const float* __restrict__ Wf, const float* __restrict__ Wi,
                             const float* __restrict__ Wo, const float* __restrict__ Wc,
                             bf16* __restrict__ out)
{
    int idx = blockIdx.x * 256 + threadIdx.x;  // 3*1024*256
    int k = idx & 255, n = (idx >> 8) & 1023, l = idx >> 18;
    int j = n >> 2, g = n & 3;
    const float* src = (g == 0) ? Wf : (g == 1) ? Wi : (g == 2) ? Wo : Wc;
    out[idx] = __float2bfloat16(src[l * 65536 + j * 256 + k]);
}

__global__ void build_whfio(const float* __restrict__ Wf, const float* __restrict__ Wi,
                            const float* __restrict__ Wo, bf16* __restrict__ out)
{
    int idx = blockIdx.x * 256 + threadIdx.x;  // 3*768*256
    int k = idx & 255, n = (idx >> 8) % 768, l = idx / 196608;
    const float* src = (n < 256) ? Wf : (n < 512) ? Wi : Wo;
    out[idx] = __float2bfloat16(src[l * 65536 + (n & 255) * 256 + k]);
}

__global__ void build_wg(const float* __restrict__ Wig, bf16* __restrict__ out)
{
    int idx = blockIdx.x * 256 + threadIdx.x;  // 3*16*256
    int k = idx & 255, r = (idx >> 8) & 15, l = idx >> 12;
    out[idx] = (r < 3) ? __float2bfloat16(Wig[l * 768 + r * 256 + k]) : __float2bfloat16(0.f);
}

// WgH [3][16][768]: rows 0..2 = Wh_g[l], rest zero
__global__ void build_wgh(const float* __restrict__ Whg, bf16* __restrict__ out)
{
    int idx = blockIdx.x * 256 + threadIdx.x;  // 3*16*768
    int k = idx % 768, r = (idx / 768) & 15, l = idx / (16 * 768);
    out[idx] = (r < 3) ? __float2bfloat16(Whg[(l * 3 + r) * 768 + k]) : __float2bfloat16(0.f);
}

__global__ void build_wlast(const float* __restrict__ Wl, bf16* __restrict__ out)
{
    int idx = blockIdx.x * 256 + threadIdx.x;  // 128*2304
    int k = idx % 2304, n = idx / 2304;
    out[idx] = (n < 44) ? __float2bfloat16(Wl[n * 2304 + k]) : __float2bfloat16(0.f);
}

__global__ void convert_f2b(const float* __restrict__ in, bf16* __restrict__ out, int n)
{
    int idx = blockIdx.x * 256 + threadIdx.x;
    if (idx < n) out[idx] = __float2bfloat16(in[idx]);
}

__global__ void init_state(const float* __restrict__ hidden0, const float* __restrict__ current0,
                           bf16* __restrict__ hcat, float* __restrict__ c0)
{
    int idx = blockIdx.x * 256 + threadIdx.x;  // 3*4096*256
    int j = idx & 255, b = (idx >> 8) & 4095, l = idx >> 20;
    hcat[(size_t)b * 768 + l * 256 + j] = __float2bfloat16(hidden0[idx]);
    c0[idx] = current0[idx];
}

extern "C" void kernel_launch(void* const* d_in, const int* in_sizes, int n_in,
                              void* d_out, int out_size, void* d_ws, size_t ws_size,
                              hipStream_t stream)
{
    (void)in_sizes; (void)n_in; (void)out_size; (void)ws_size;
    const float* x        = (const float*)d_in[0];
    const float* hidden0  = (const float*)d_in[1];
    const float* current0 = (const float*)d_in[2];
    const float* Wi_f = (const float*)d_in[3];  const float* bi_f = (const float*)d_in[4];
    const float* Wi_i = (const float*)d_in[5];  const float* bi_i = (const float*)d_in[6];
    const float* Wi_o = (const float*)d_in[7];  const float* bi_o = (const float*)d_in[8];
    const float* Wi_c = (const float*)d_in[9];  const float* bi_c = (const float*)d_in[10];
    const float* Wi_g = (const float*)d_in[11]; const float* bi_g = (const float*)d_in[12];
    const float* Wh_f = (const float*)d_in[13]; const float* bh_f = (const float*)d_in[14];
    const float* Wh_i = (const float*)d_in[15]; const float* bh_i = (const float*)d_in[16];
    const float* Wh_o = (const float*)d_in[17]; const float* bh_o = (const float*)d_in[18];
    const float* Wh_g = (const float*)d_in[19]; const float* bh_g = (const float*)d_in[20];
    const float* Wh_c = (const float*)d_in[21]; const float* bh_c = (const float*)d_in[22];
    const float* W_last = (const float*)d_in[23]; const float* b_last = (const float*)d_in[24];

    char* p = (char*)d_ws;
    bf16* WiCatI = (bf16*)p; p += (size_t)3 * 1024 * 256 * 2;
    bf16* WhFIO  = (bf16*)p; p += (size_t)3 * 768 * 256 * 2;
    bf16* WhCb   = (bf16*)p; p += (size_t)3 * 768 * 768 * 2;
    bf16* Wgb    = (bf16*)p; p += (size_t)3 * 16 * 256 * 2;
    bf16* WgH    = (bf16*)p; p += (size_t)3 * 16 * 768 * 2;
    bf16* Wlb    = (bf16*)p; p += (size_t)128 * 2304 * 2;
    bf16* xb     = (bf16*)p; p += (size_t)4096 * 256 * 2;
    bf16* ipre0i = (bf16*)p; p += (size_t)4096 * 1024 * 2;
    float* gin0  = (float*)p; p += (size_t)4096 * 3 * 4;
    bf16* hb0    = (bf16*)p; p += (size_t)4096 * 768 * 2;
    bf16* hb1    = (bf16*)p; p += (size_t)4096 * 768 * 2;
    float* cb0   = (float*)p; p += (size_t)3 * 4096 * 256 * 4;
    float* cb1   = (float*)p; p += (size_t)3 * 4096 * 256 * 4;
    bf16* hgb    = (bf16*)p; p += (size_t)3 * 4096 * 768 * 2;
    bf16* auxb   = (bf16*)p; p += (size_t)3 * 4096 * 768 * 2;
    float* gh    = (float*)p; p += (size_t)4096 * 9 * 4;
    bf16* feat   = (bf16*)p; p += (size_t)4096 * 2304 * 2;
    float* partf = (float*)p; p += (size_t)12 * 4096 * 64 * 4;

    build_wicati<<<3072, 256, 0, stream>>>(Wi_f, Wi_i, Wi_o, Wi_c, WiCatI);
    build_whfio<<<2304, 256, 0, stream>>>(Wh_f, Wh_i, Wh_o, WhFIO);
    convert_f2b<<<(3 * 768 * 768 + 255) / 256, 256, 0, stream>>>(Wh_c, WhCb, 3 * 768 * 768);
    build_wg<<<48, 256, 0, stream>>>(Wi_g, Wgb);
    build_wgh<<<144, 256, 0, stream>>>(Wh_g, WgH);
    build_wlast<<<1152, 256, 0, stream>>>(W_last, Wlb);
    convert_f2b<<<4096, 256, 0, stream>>>(x, xb, 4096 * 256);
    init_state<<<12288, 256, 0, stream>>>(hidden0, current0, hb0, cb0);

    // hoisted layer-0 input-side work (x constant across t)
    gemm_bt<<<dim3(8, 32, 1), 256, 0, stream>>>(xb, 256, 0, WiCatI, 256, 0,
                                                ipre0i, 1024, 0, 256, 1, nullptr, 0);
    gin0_kernel<<<256, 256, 0, stream>>>(xb, Wi_g, gin0);

    for (int t = 0; t < 10; ++t) {
        bf16* hprev = (t & 1) ? hb1 : hb0;
        bf16* hnew  = (t & 1) ? hb0 : hb1;
        float* cprev = (t & 1) ? cb1 : cb0;
        float* cnew  = (t & 1) ? cb0 : cb1;

        gemm_hidden<<<dim3(36, 32), 256, 0, stream>>>(
            hprev, WhFIO, WhCb, WgH, bi_g, bh_g, hgb, auxb, gh);

        gates_pre<<<1024, 256, 0, stream>>>(
            ipre0i, gin0, gh,
            hgb, auxb, cprev,
            bi_f, bh_f, bi_i, bh_i, bi_o, bh_o, bi_c, bh_c,
            hnew, cnew);

        for (int l = 1; l < 3; ++l) {
            gemm_gates<<<dim3(8, 64), 256, 0, stream>>>(
                (const bf16*)(hnew + (l - 1) * 256), 768,
                WiCatI + (size_t)l * 1024 * 256,
                Wgb + (size_t)l * 16 * 256,
                hgb + (size_t)l * 4096 * 768,
                auxb + (size_t)l * 4096 * 768,
                gh + l * 3,
                cprev + (size_t)l * 4096 * 256,
                bi_f + l * 256, bh_f + l * 256,
                bi_i + l * 256, bh_i + l * 256,
                bi_o + l * 256, bh_o + l * 256,
                bi_c + l * 256, bh_c + l * 768,
                hnew + l * 256,
                cnew + (size_t)l * 4096 * 256,
                (l == 2 && t < 9) ? (feat + (size_t)t * 256) : (bf16*)nullptr);
        }
    }

    // final: K-split feat[4096,2304] @ Wlb[128,2304]^T into 12 partials of K=192
    gemm_bt<<<dim3(1, 32, 12), 256, 0, stream>>>(
        feat, 2304, 192, Wlb, 2304, 192,
        partf, 64, (long long)4096 * 64, 192, 3, nullptr, 64);
    final_reduce<<<704, 256, 0, stream>>>(partf, b_last, (float*)d_out);
}